// Round 8
// baseline (607.916 us; speedup 1.0000x reference)
//
#include <hip/hip_runtime.h>
#include <hip/hip_bf16.h>
#include <math.h>

// GLA block, MI355X. Round 8: barrier-free direct-fragment GEMM (no LDS):
// each 64-thread block = one wave computing a 64x64 tile; A/B MFMA fragments
// are 16B-contiguous in row-major [M][K]/[N][K], loaded straight to VGPRs with
// manual double-buffering. Non-GEMM pipeline identical to round 6 (456 us).

using bf16 = __hip_bfloat16;
typedef __attribute__((ext_vector_type(8))) short bf16x8;
typedef __attribute__((ext_vector_type(4))) float f32x4;

#define BT 4096
#define HM 1024
#define DK 32
#define DV 64
#define NC 32
#define CHK 64

__device__ __forceinline__ float b2f(bf16 v) { return __bfloat162float(v); }
__device__ __forceinline__ bf16 f2b(float v) { return __float2bfloat16(v); }
__device__ __forceinline__ float clampf(float v, float lim) {
    return fminf(fmaxf(v, -lim), lim);
}
__device__ __forceinline__ float lo16(unsigned int u) {
    union { unsigned int i; float f; } c; c.i = u << 16; return c.f;
}
__device__ __forceinline__ float hi16(unsigned int u) {
    union { unsigned int i; float f; } c; c.i = u & 0xffff0000u; return c.f;
}
__device__ __forceinline__ void acc8(float a, uint4 r, float* o) {
    o[0] += a * lo16(r.x); o[1] += a * hi16(r.x);
    o[2] += a * lo16(r.y); o[3] += a * hi16(r.y);
    o[4] += a * lo16(r.z); o[5] += a * hi16(r.z);
    o[6] += a * lo16(r.w); o[7] += a * hi16(r.w);
}

// ---------------- dtype detector ----------------
__global__ __launch_bounds__(256) void detect_dtype(
    const unsigned int* __restrict__ x, int* __restrict__ flag)
{
    int tid = threadIdx.x;
    int cnt = 0;
    for (int i = 0; i < 16; ++i) {
        unsigned int w = x[tid * 16 + i];
        unsigned int e_lo = (w >> 7) & 0xffu;
        unsigned int e_hi = (w >> 23) & 0xffu;
        cnt += (e_lo >= 110 && e_lo <= 135 && e_hi >= 110 && e_hi <= 135) ? 1 : 0;
    }
    __shared__ int red[256];
    red[tid] = cnt;
    __syncthreads();
    for (int s = 128; s > 0; s >>= 1) {
        if (tid < s) red[tid] += red[tid + s];
        __syncthreads();
    }
    if (tid == 0) *flag = (red[0] > 2048) ? 1 : 0;  // 1 = bf16 buffers, 0 = f32
}

// ---------------- canonicalize x -> bf16 ----------------
__global__ __launch_bounds__(256) void cvt_to_bf16(
    const void* __restrict__ src, bf16* __restrict__ dst, int n,
    const int* __restrict__ flag)
{
    bool isb = (*flag != 0);
    int i = blockIdx.x * 256 + threadIdx.x;
    int stride = gridDim.x * 256;
    for (; i < n; i += stride) {
        if (isb) ((ushort*)dst)[i] = ((const ushort*)src)[i];
        else     dst[i] = f2b(((const float*)src)[i]);
    }
}

// ---------------- fused small-tensor cvt ----------
struct SmallCvt { const void* s[8]; bf16* d[8]; int n[8]; };
__global__ __launch_bounds__(256) void cvt_small(SmallCvt sc, const int* __restrict__ flag)
{
    bool isb = (*flag != 0);
    int stride = gridDim.x * 256;
    #pragma unroll
    for (int seg = 0; seg < 8; ++seg) {
        int n = sc.n[seg];
        for (int i = blockIdx.x * 256 + threadIdx.x; i < n; i += stride) {
            if (isb) ((ushort*)sc.d[seg])[i] = ((const ushort*)sc.s[seg])[i];
            else     sc.d[seg][i] = f2b(((const float*)sc.s[seg])[i]);
        }
    }
}

// ---------------- transpose (+cvt): src[R][C] -> dst[C][R] bf16 --------------
__global__ __launch_bounds__(256) void transpose_any(
    const void* __restrict__ src, ushort* __restrict__ dst, int R, int C,
    const int* __restrict__ flag)
{
    bool isb = (*flag != 0);
    __shared__ ushort tile[32][33];
    int c0 = blockIdx.x * 32, r0 = blockIdx.y * 32;
    int x = threadIdx.x, y = threadIdx.y;  // 32 x 8
    #pragma unroll
    for (int dy = 0; dy < 32; dy += 8) {
        size_t idx = (size_t)(r0 + y + dy) * C + c0 + x;
        ushort v;
        if (isb) v = ((const ushort*)src)[idx];
        else { bf16 t = f2b(((const float*)src)[idx]); v = *(ushort*)&t; }
        tile[y + dy][x] = v;
    }
    __syncthreads();
    #pragma unroll
    for (int dy = 0; dy < 32; dy += 8)
        dst[(size_t)(c0 + y + dy) * R + r0 + x] = tile[x][y + dy];
}

// ---------------- LayerNorm ----------------
template <typename TI>
__global__ __launch_bounds__(256) void ln_kernel(
    const TI* __restrict__ x, const bf16* __restrict__ w, const bf16* __restrict__ b,
    bf16* __restrict__ out)
{
    size_t base = (size_t)blockIdx.x * HM;
    int tid = threadIdx.x;
    float v[4], s = 0.f, s2 = 0.f;
    #pragma unroll
    for (int u = 0; u < 4; ++u) {
        float f;
        if constexpr (sizeof(TI) == 2) f = b2f(((const bf16*)x)[base + tid + u * 256]);
        else                           f = ((const float*)x)[base + tid + u * 256];
        v[u] = f; s += f; s2 += f * f;
    }
    #pragma unroll
    for (int off = 32; off >= 1; off >>= 1) {
        s  += __shfl_down(s, off);
        s2 += __shfl_down(s2, off);
    }
    __shared__ float ra[4], rb[4];
    int wave = tid >> 6;
    if ((tid & 63) == 0) { ra[wave] = s; rb[wave] = s2; }
    __syncthreads();
    s = ra[0] + ra[1] + ra[2] + ra[3];
    s2 = rb[0] + rb[1] + rb[2] + rb[3];
    float mean = s * (1.f / HM);
    float var = fmaxf(s2 * (1.f / HM) - mean * mean, 0.f);
    float rs = rsqrtf(var + 1e-5f);
    #pragma unroll
    for (int u = 0; u < 4; ++u) {
        int col = tid + u * 256;
        out[base + col] = f2b((v[u] - mean) * rs * b2f(w[col]) + b2f(b[col]));
    }
}

// ---------------- gate low-rank MLP ----------------
__global__ __launch_bounds__(256) void gk_kernel(
    const bf16* __restrict__ h, const bf16* __restrict__ w1,
    const bf16* __restrict__ w2, const bf16* __restrict__ b2i,
    bf16* __restrict__ gkout)
{
    size_t row = blockIdx.x;
    const bf16* hr = h + row * HM;
    int tid = threadIdx.x;
    int d = tid & 15, seg = tid >> 4;
    float s = 0.f;
    for (int j = 0; j < 64; ++j) {
        int i = seg * 64 + j;
        s += b2f(hr[i]) * b2f(w1[i * 16 + d]);
    }
    __shared__ float red[256];
    __shared__ float g1[16];
    red[tid] = s;
    __syncthreads();
    if (tid < 16) {
        float t = 0.f;
        #pragma unroll
        for (int sg = 0; sg < 16; ++sg) t += red[sg * 16 + tid];
        g1[tid] = t;
    }
    __syncthreads();
    #pragma unroll
    for (int rep = 0; rep < 2; ++rep) {
        int n = tid + rep * 256;
        float z = b2f(b2i[n]);
        #pragma unroll
        for (int r = 0; r < 16; ++r) z += g1[r] * b2f(w2[r * 512 + n]);
        z = clampf(z, 30.f);
        float ls = (z >= 0.f) ? -log1pf(expf(-z)) : (z - log1pf(expf(z)));
        gkout[row * 512 + n] = f2b(ls * 0.0625f);
    }
}

// ---------------- direct-fragment GEMM: one wave per 64x64 tile -------------
// A[M][K], Wt[N][K] row-major bf16. Fragment of lane l for 16x16x32 MFMA is
// 16 contiguous bytes: A[row16 + 16*mi][k0 + quad*8 .. +7]. Load straight to
// VGPRs, no LDS, no barriers. Manual double-buffer over K (BK=32, 2 stages).
// MODE 0: ->bf16; 1: f32 = resid_bf16+acc; 2: bf16 = gelu(acc+bias);
// MODE 3: resid_f32+acc+bias -> f32 or bf16 per oflag
template <int MODE>
__global__ __launch_bounds__(64) void dgemm(
    const bf16* __restrict__ A, const bf16* __restrict__ Wt,
    const bf16* __restrict__ bias, const void* __restrict__ resid,
    void* __restrict__ out, int M, int N, int K, const int* __restrict__ oflag)
{
    int l = threadIdx.x;
    int bm = blockIdx.x * 64, bn = blockIdx.y * 64;
    int row16 = l & 15, quad = l >> 4;
    bool out_bf16 = false;
    if constexpr (MODE == 3) out_bf16 = (*oflag != 0);

    const ushort* Au = (const ushort*)A;
    const ushort* Wu = (const ushort*)Wt;
    const ushort* pa[4];
    const ushort* pb[4];
    #pragma unroll
    for (int mi = 0; mi < 4; ++mi)
        pa[mi] = Au + (size_t)(bm + mi * 16 + row16) * K + quad * 8;
    #pragma unroll
    for (int ni = 0; ni < 4; ++ni)
        pb[ni] = Wu + (size_t)(bn + ni * 16 + row16) * K + quad * 8;

    f32x4 acc[4][4] = {};
    bf16x8 a0[4], b0[4], a1[4], b1[4];
    #pragma unroll
    for (int mi = 0; mi < 4; ++mi) a0[mi] = *(const bf16x8*)(pa[mi]);
    #pragma unroll
    for (int ni = 0; ni < 4; ++ni) b0[ni] = *(const bf16x8*)(pb[ni]);

    for (int k0 = 0; k0 < K; k0 += 64) {
        // prefetch stage 1 (k0+32) while computing stage 0
        #pragma unroll
        for (int mi = 0; mi < 4; ++mi) a1[mi] = *(const bf16x8*)(pa[mi] + k0 + 32);
        #pragma unroll
        for (int ni = 0; ni < 4; ++ni) b1[ni] = *(const bf16x8*)(pb[ni] + k0 + 32);
        #pragma unroll
        for (int mi = 0; mi < 4; ++mi)
            #pragma unroll
            for (int ni = 0; ni < 4; ++ni)
                acc[mi][ni] = __builtin_amdgcn_mfma_f32_16x16x32_bf16(a0[mi], b0[ni], acc[mi][ni], 0, 0, 0);
        // prefetch next stage 0 (k0+64) while computing stage 1
        if (k0 + 64 < K) {
            #pragma unroll
            for (int mi = 0; mi < 4; ++mi) a0[mi] = *(const bf16x8*)(pa[mi] + k0 + 64);
            #pragma unroll
            for (int ni = 0; ni < 4; ++ni) b0[ni] = *(const bf16x8*)(pb[ni] + k0 + 64);
        }
        #pragma unroll
        for (int mi = 0; mi < 4; ++mi)
            #pragma unroll
            for (int ni = 0; ni < 4; ++ni)
                acc[mi][ni] = __builtin_amdgcn_mfma_f32_16x16x32_bf16(a1[mi], b1[ni], acc[mi][ni], 0, 0, 0);
    }

    #pragma unroll
    for (int mi = 0; mi < 4; ++mi) {
        #pragma unroll
        for (int ni = 0; ni < 4; ++ni) {
            int col = bn + ni * 16 + row16;
            #pragma unroll
            for (int r = 0; r < 4; ++r) {
                int row = bm + mi * 16 + quad * 4 + r;
                size_t idx = (size_t)row * N + col;
                float v = acc[mi][ni][r];
                if constexpr (MODE == 0) {
                    ((bf16*)out)[idx] = f2b(clampf(v, 1e4f));
                } else if constexpr (MODE == 1) {
                    ((float*)out)[idx] = clampf(b2f(((const bf16*)resid)[idx]) + v, 1e5f);
                } else if constexpr (MODE == 2) {
                    float t = clampf(v + b2f(bias[col]), 50.f);
                    ((bf16*)out)[idx] = f2b(0.5f * t * (1.f + erff(t * 0.70710678f)));
                } else {
                    float t = clampf(v + b2f(bias[col]) + ((const float*)resid)[idx], 2e5f);
                    if (out_bf16) ((bf16*)out)[idx] = f2b(t);
                    else          ((float*)out)[idx] = t;
                }
            }
        }
    }
}

// ---------------- GLA phase 1 (qvg stride 3072) ----------------
__global__ __launch_bounds__(256) void gla_phase1(
    const bf16* __restrict__ gkb,   // [4096][512]
    const bf16* __restrict__ qvg,   // [4096][3072]: q 0-511, k 512-1023, v 1024-2047, g 2048-3071
    float* __restrict__ clbuf, float* __restrict__ Dbuf, float* __restrict__ Pbuf)
{
    int bh = blockIdx.x, c = blockIdx.y;
    int b = bh >> 4, hh = bh & 15;
    int row0 = b * 2048 + c * CHK;
    __shared__ float glog[CHK][DK + 1];
    __shared__ float wk[CHK][DK + 1];
    __shared__ __align__(16) ushort vt[CHK][DV];
    int tid = threadIdx.x;
    int k = tid & 31, i8 = (tid >> 5) * 8;
    #pragma unroll
    for (int u = 0; u < 8; ++u) {
        int i = i8 + u;
        float g = b2f(gkb[(size_t)(row0 + i) * 512 + hh * 32 + k]);
        glog[i][k] = fminf(fmaxf(g, -2.f), 0.f);
    }
    {
        int cc = tid & 7, ii = tid >> 3;
        #pragma unroll
        for (int h = 0; h < 2; ++h) {
            int i = ii + h * 32;
            uint4 val = *(const uint4*)((const ushort*)qvg + (size_t)(row0 + i) * 3072 + 1024 + hh * 64 + cc * 8);
            *(uint4*)&vt[i][cc * 8] = val;
        }
    }
    __syncthreads();
    if (tid < 32) {
        float run = 0.f;
        for (int j = 0; j < CHK; ++j) { run += glog[j][tid]; glog[j][tid] = run; }
    }
    __syncthreads();
    #pragma unroll
    for (int u = 0; u < 8; ++u) {
        int i = i8 + u;
        float cl = glog[i][k];
        float cl63 = glog[CHK - 1][k];
        clbuf[(size_t)(row0 + i) * 512 + hh * 32 + k] = cl;
        wk[i][k] = expf(fmaxf(cl63 - cl, -60.f)) *
            b2f(qvg[(size_t)(row0 + i) * 3072 + 512 + hh * 32 + k]);
    }
    if (tid < 32) Dbuf[(size_t)(bh * 32 + c) * 32 + tid] = expf(glog[CHK - 1][tid]);
    __syncthreads();
    int kk = tid >> 3, v8 = (tid & 7) * 8;
    float acc[8] = {};
    for (int j = 0; j < CHK; ++j) {
        float w = wk[j][kk];
        uint4 raw = *(const uint4*)&vt[j][v8];
        acc8(w, raw, acc);
    }
    float* Pp = Pbuf + (size_t)(bh * 32 + c) * 2048 + kk * 64 + v8;
    #pragma unroll
    for (int u = 0; u < 8; ++u) Pp[u] = acc[u];
}

// ---------------- GLA phase 2: scan ----------------
__global__ __launch_bounds__(256) void gla_scan(
    const float* __restrict__ Pbuf, const float* __restrict__ Dbuf,
    float* __restrict__ Sbuf)
{
    int bh = blockIdx.x >> 3, vg8 = blockIdx.x & 7;
    int kk = threadIdx.x >> 3, vv = vg8 * 8 + (threadIdx.x & 7);
    float S = 0.f;
    for (int c = 0; c < NC; ++c) {
        size_t idx = (size_t)(bh * 32 + c) * 2048 + kk * 64 + vv;
        float P = Pbuf[idx];
        float D = Dbuf[(size_t)(bh * 32 + c) * 32 + kk];
        Sbuf[idx] = S;
        S = D * S + P;
    }
}

// ---------------- GLA phase 3 (qvg stride 3072) ----------------
__global__ __launch_bounds__(256) void gla_phase3(
    const bf16* __restrict__ qvg,
    const float* __restrict__ clbuf, const float* __restrict__ Sbuf,
    const bf16* __restrict__ rmsw, bf16* __restrict__ obuf)
{
    int bh = blockIdx.x, c = blockIdx.y;
    int b = bh >> 4, hh = bh & 15;
    int row0 = b * 2048 + c * CHK;
    __shared__ float qs[CHK][36], ks[CHK][36];
    __shared__ float S0[DK][68];
    __shared__ float Amat[CHK][CHK + 1];
    __shared__ __align__(16) ushort vt[CHK][DV];
    int tid = threadIdx.x;
    {
        int k = tid & 31, i8 = (tid >> 5) * 8;
        #pragma unroll
        for (int u = 0; u < 8; ++u) {
            int i = i8 + u;
            size_t r = (size_t)(row0 + i);
            int col = hh * 32 + k;
            float cl = fmaxf(clbuf[r * 512 + col], -60.f);
            qs[i][k] = b2f(qvg[r * 3072 + col]) * expf(cl) * 0.17677669529663687f;
            ks[i][k] = b2f(qvg[r * 3072 + 512 + col]) * expf(-cl);
        }
    }
    {
        int cc = tid & 7, ii = tid >> 3;
        #pragma unroll
        for (int h = 0; h < 2; ++h) {
            int i = ii + h * 32;
            uint4 val = *(const uint4*)((const ushort*)qvg + (size_t)(row0 + i) * 3072 + 1024 + hh * 64 + cc * 8);
            *(uint4*)&vt[i][cc * 8] = val;
        }
    }
    {
        int kk = tid >> 3, v8 = (tid & 7) * 8;
        const float* Sp = Sbuf + (size_t)(bh * 32 + c) * 2048 + kk * 64 + v8;
        *(f32x4*)&S0[kk][v8]     = *(const f32x4*)Sp;
        *(f32x4*)&S0[kk][v8 + 4] = *(const f32x4*)(Sp + 4);
    }
    __syncthreads();
    int i = tid >> 2, jb = tid & 3;
    for (int jj = 0; jj < 16; ++jj) {
        int j = jb + jj * 4;
        float d = 0.f;
        if (j <= i) {
            const f32x4* qp = (const f32x4*)qs[i];
            const f32x4* kp = (const f32x4*)ks[j];
            #pragma unroll
            for (int q8 = 0; q8 < 8; ++q8) {
                f32x4 a = qp[q8], bq = kp[q8];
                d += a.x * bq.x + a.y * bq.y + a.z * bq.z + a.w * bq.w;
            }
        }
        Amat[i][j] = d;
    }
    __syncthreads();
    float o[16] = {};
    int vv = jb * 16;
    for (int j = 0; j < CHK; ++j) {
        float a = Amat[i][j];
        uint4 r0 = *(const uint4*)&vt[j][vv];
        uint4 r1 = *(const uint4*)&vt[j][vv + 8];
        acc8(a, r0, o);
        acc8(a, r1, o + 8);
    }
    #pragma unroll
    for (int kk = 0; kk < DK; ++kk) {
        float qv = qs[i][kk];
        const f32x4* Sp = (const f32x4*)&S0[kk][vv];
        #pragma unroll
        for (int q4 = 0; q4 < 4; ++q4) {
            f32x4 sv = Sp[q4];
            o[q4 * 4 + 0] += qv * sv.x; o[q4 * 4 + 1] += qv * sv.y;
            o[q4 * 4 + 2] += qv * sv.z; o[q4 * 4 + 3] += qv * sv.w;
        }
    }
    float ss = 0.f;
    #pragma unroll
    for (int u = 0; u < 16; ++u) ss += o[u] * o[u];
    ss += __shfl_xor(ss, 1);
    ss += __shfl_xor(ss, 2);
    float sc = rsqrtf(fmaxf(ss, 0.f) * (1.f / DV) + 1e-5f);
    size_t r = (size_t)(row0 + i);
    #pragma unroll
    for (int u = 0; u < 16; ++u) {
        float g = b2f(qvg[r * 3072 + 2048 + hh * 64 + vv + u]);
        float sw = g / (1.f + expf(-g));
        obuf[r * 1024 + hh * 64 + vv + u] = f2b(clampf(o[u] * sc * b2f(rmsw[vv + u]) * sw, 3e4f));
    }
}

// ---------------- launcher ----------------
extern "C" void kernel_launch(void* const* d_in, const int* in_sizes, int n_in,
                              void* d_out, int out_size, void* d_ws, size_t ws_size,
                              hipStream_t stream) {
    (void)in_sizes; (void)n_in; (void)out_size; (void)ws_size;

    char* ws = (char*)d_ws;
    const size_t MB = 1024 * 1024;
    const size_t KB = 1024;
    bf16*  WqkT = (bf16*)(ws + 0);          // 0-2 MB  (combined [3072][1024] with WvgT)
    bf16*  WkT  = (bf16*)(ws + 1 * MB);
    bf16*  WvgT = (bf16*)(ws + 2 * MB);     // 2-6 MB
    bf16*  WgT  = (bf16*)(ws + 4 * MB);
    bf16*  WoT  = (bf16*)(ws + 6 * MB);     // 6-8
    bf16*  W1T  = (bf16*)(ws + 8 * MB);     // 8-12
    bf16*  W2T  = (bf16*)(ws + 12 * MB);    // 12-16
    bf16*  hbuf = (bf16*)(ws + 16 * MB);    // 16-24 (h, later h2)
    bf16*  qvg  = (bf16*)(ws + 24 * MB);    // 24-48 [4096][3072] (dead after phase3)
    bf16*  gkb  = (bf16*)(ws + 48 * MB);    // 48-52 (dead after phase1)
    float* clbf = (float*)(ws + 52 * MB);   // 52-60 (dead after phase3)
    float* Dbuf = (float*)(ws + 60 * MB);   // 60-61 (dead after scan)
    float* Pbuf = (float*)(ws + 61 * MB);   // 61-69 (dead after scan)
    float* Sbuf = (float*)(ws + 69 * MB);   // 69-77 (dead after phase3)
    bf16*  obuf = (bf16*)(ws + 61 * MB);    // aliases Pbuf (dead)
    float* ybuf = (float*)(ws + 32 * MB);   // 32-48, aliases qvg tail (dead after phase3)
    bf16*  f1   = (bf16*)(ws + 48 * MB);    // 48-64, aliases gkb/clbf/Dbuf/obuf-head (dead)
    bf16*  cx   = (bf16*)(ws + 77 * MB);    // 77-85
    bf16*  clnw = (bf16*)(ws + 85 * MB);
    bf16*  clnb = (bf16*)(ws + 85 * MB + 64 * KB);
    bf16*  cgw1 = (bf16*)(ws + 85 * MB + 128 * KB);
    bf16*  cgw2 = (bf16*)(ws + 85 * MB + 192 * KB);
    bf16*  cgb2 = (bf16*)(ws + 85 * MB + 256 * KB);
    bf16*  crms = (bf16*)(ws + 85 * MB + 320 * KB);
    bf16*  cb1  = (bf16*)(ws + 85 * MB + 384 * KB);
    bf16*  cb2  = (bf16*)(ws + 85 * MB + 448 * KB);
    int*   flag = (int*)(ws + 85 * MB + 512 * KB);

    // 1. detect dtype
    hipLaunchKernelGGL(detect_dtype, dim3(1), dim3(256), 0, stream,
                       (const unsigned int*)d_in[0], flag);

    // 2. canonicalize x + small tensors
    hipLaunchKernelGGL(cvt_to_bf16, dim3(2048), dim3(256), 0, stream,
                       d_in[0], cx, 4194304, flag);
    SmallCvt sc;
    sc.s[0] = d_in[1];  sc.d[0] = clnw; sc.n[0] = 1024;
    sc.s[1] = d_in[2];  sc.d[1] = clnb; sc.n[1] = 1024;
    sc.s[2] = d_in[6];  sc.d[2] = cgw1; sc.n[2] = 16384;
    sc.s[3] = d_in[7];  sc.d[3] = cgw2; sc.n[3] = 8192;
    sc.s[4] = d_in[8];  sc.d[4] = cgb2; sc.n[4] = 512;
    sc.s[5] = d_in[10]; sc.d[5] = crms; sc.n[5] = 64;
    sc.s[6] = d_in[13]; sc.d[6] = cb1;  sc.n[6] = 2048;
    sc.s[7] = d_in[15]; sc.d[7] = cb2;  sc.n[7] = 1024;
    hipLaunchKernelGGL(cvt_small, dim3(64), dim3(256), 0, stream, sc, flag);

    // 3. fused cvt+transpose of the 7 big weights
    dim3 tb(32, 8);
    hipLaunchKernelGGL(transpose_any, dim3(16, 32), tb, 0, stream, d_in[3],  (ushort*)WqkT, 1024, 512, flag);
    hipLaunchKernelGGL(transpose_any, dim3(16, 32), tb, 0, stream, d_in[4],  (ushort*)WkT,  1024, 512, flag);
    hipLaunchKernelGGL(transpose_any, dim3(32, 32), tb, 0, stream, d_in[5],  (ushort*)WvgT, 1024, 1024, flag);
    hipLaunchKernelGGL(transpose_any, dim3(32, 32), tb, 0, stream, d_in[9],  (ushort*)WgT,  1024, 1024, flag);
    hipLaunchKernelGGL(transpose_any, dim3(32, 32), tb, 0, stream, d_in[11], (ushort*)WoT,  1024, 1024, flag);
    hipLaunchKernelGGL(transpose_any, dim3(64, 32), tb, 0, stream, d_in[12], (ushort*)W1T,  1024, 2048, flag);
    hipLaunchKernelGGL(transpose_any, dim3(32, 64), tb, 0, stream, d_in[14], (ushort*)W2T,  2048, 1024, flag);

    // 4. pipeline
    hipLaunchKernelGGL((ln_kernel<bf16>), dim3(BT), dim3(256), 0, stream, cx, clnw, clnb, hbuf);

    // fused q|k|v|g projection: N=3072 (weights contiguous at WqkT)
    hipLaunchKernelGGL((dgemm<0>), dim3(64, 48), dim3(64), 0, stream,
                       hbuf, WqkT, (const bf16*)nullptr, (const void*)nullptr, (void*)qvg, BT, 3072, 1024, (const int*)nullptr);
    hipLaunchKernelGGL(gk_kernel, dim3(BT), dim3(256), 0, stream, hbuf, cgw1, cgw2, cgb2, gkb);

    hipLaunchKernelGGL(gla_phase1, dim3(32, 32), dim3(256), 0, stream, gkb, qvg, clbf, Dbuf, Pbuf);
    hipLaunchKernelGGL(gla_scan, dim3(256), dim3(256), 0, stream, Pbuf, Dbuf, Sbuf);
    hipLaunchKernelGGL(gla_phase3, dim3(32, 32), dim3(256), 0, stream, qvg, clbf, Sbuf, crms, obuf);

    hipLaunchKernelGGL((dgemm<1>), dim3(64, 16), dim3(64), 0, stream,
                       obuf, WoT, (const bf16*)nullptr, (const void*)cx, (void*)ybuf, BT, 1024, 1024, (const int*)nullptr);
    hipLaunchKernelGGL((ln_kernel<float>), dim3(BT), dim3(256), 0, stream, ybuf, clnw, clnb, hbuf);
    hipLaunchKernelGGL((dgemm<2>), dim3(64, 32), dim3(64), 0, stream,
                       hbuf, W1T, cb1, (const void*)nullptr, (void*)f1, BT, 2048, 1024, (const int*)nullptr);
    hipLaunchKernelGGL((dgemm<3>), dim3(64, 16), dim3(64), 0, stream,
                       f1, W2T, cb2, (const void*)ybuf, d_out, BT, 1024, 2048, flag);
}

// Round 9
// 445.023 us; speedup vs baseline: 1.3660x; 1.3660x over previous
//
#include <hip/hip_runtime.h>
#include <hip/hip_bf16.h>
#include <math.h>

// GLA block, MI355X. Round 9: round-6 GEMM restored (best measured) + XCD
// swizzle; removed x-cvt pass (ln + Wo-resid read raw input per dtype flag);
// 7 transposes fused into one launch. 13 dispatches total (was 24).

using bf16 = __hip_bfloat16;
typedef __attribute__((ext_vector_type(8))) short bf16x8;
typedef __attribute__((ext_vector_type(4))) float f32x4;

#define BT 4096
#define HM 1024
#define DK 32
#define DV 64
#define NC 32
#define CHK 64

#if defined(__has_builtin)
#if __has_builtin(__builtin_amdgcn_global_load_lds)
#define HAVE_GLDS 1
#endif
#endif

#ifdef HAVE_GLDS
#define GLDS16(g, l) __builtin_amdgcn_global_load_lds( \
    (const __attribute__((address_space(1))) unsigned int*)(g), \
    (__attribute__((address_space(3))) unsigned int*)(l), 16, 0, 0)
#else
#define GLDS16(g, l) (*(int4*)(l) = *(const int4*)(g))
#endif

__device__ __forceinline__ float b2f(bf16 v) { return __bfloat162float(v); }
__device__ __forceinline__ bf16 f2b(float v) { return __float2bfloat16(v); }
__device__ __forceinline__ float clampf(float v, float lim) {
    return fminf(fmaxf(v, -lim), lim);
}
__device__ __forceinline__ float lo16(unsigned int u) {
    union { unsigned int i; float f; } c; c.i = u << 16; return c.f;
}
__device__ __forceinline__ float hi16(unsigned int u) {
    union { unsigned int i; float f; } c; c.i = u & 0xffff0000u; return c.f;
}
__device__ __forceinline__ void acc8(float a, uint4 r, float* o) {
    o[0] += a * lo16(r.x); o[1] += a * hi16(r.x);
    o[2] += a * lo16(r.y); o[3] += a * hi16(r.y);
    o[4] += a * lo16(r.z); o[5] += a * hi16(r.z);
    o[6] += a * lo16(r.w); o[7] += a * hi16(r.w);
}

// ---------------- dtype detector ----------------
__global__ __launch_bounds__(256) void detect_dtype(
    const unsigned int* __restrict__ x, int* __restrict__ flag)
{
    int tid = threadIdx.x;
    int cnt = 0;
    for (int i = 0; i < 16; ++i) {
        unsigned int w = x[tid * 16 + i];
        unsigned int e_lo = (w >> 7) & 0xffu;
        unsigned int e_hi = (w >> 23) & 0xffu;
        cnt += (e_lo >= 110 && e_lo <= 135 && e_hi >= 110 && e_hi <= 135) ? 1 : 0;
    }
    __shared__ int red[256];
    red[tid] = cnt;
    __syncthreads();
    for (int s = 128; s > 0; s >>= 1) {
        if (tid < s) red[tid] += red[tid + s];
        __syncthreads();
    }
    if (tid == 0) *flag = (red[0] > 2048) ? 1 : 0;  // 1 = bf16 buffers, 0 = f32
}

// ---------------- fused small-tensor cvt ----------
struct SmallCvt { const void* s[8]; bf16* d[8]; int n[8]; };
__global__ __launch_bounds__(256) void cvt_small(SmallCvt sc, const int* __restrict__ flag)
{
    bool isb = (*flag != 0);
    int stride = gridDim.x * 256;
    #pragma unroll
    for (int seg = 0; seg < 8; ++seg) {
        int n = sc.n[seg];
        for (int i = blockIdx.x * 256 + threadIdx.x; i < n; i += stride) {
            if (isb) ((ushort*)sc.d[seg])[i] = ((const ushort*)sc.s[seg])[i];
            else     sc.d[seg][i] = f2b(((const float*)sc.s[seg])[i]);
        }
    }
}

// ---------------- fused transpose(+cvt) of all 7 weights ---------------------
struct TDesc { const void* src; ushort* dst; int R, C, tile0; };
struct TAll { TDesc d[7]; };
__global__ __launch_bounds__(256) void transpose_all(
    TAll ta, const int* __restrict__ flag)
{
    bool isb = (*flag != 0);
    int bid = blockIdx.x;
    int seg = 0;
    #pragma unroll
    for (int i = 1; i < 7; ++i) if (bid >= ta.d[i].tile0) seg = i;
    const void* src = ta.d[seg].src;
    ushort* dst = ta.d[seg].dst;
    int R = ta.d[seg].R, C = ta.d[seg].C;
    int t = bid - ta.d[seg].tile0;
    int tilesX = C >> 5;
    int c0 = (t % tilesX) * 32, r0 = (t / tilesX) * 32;

    __shared__ ushort tile[32][33];
    int x = threadIdx.x, y = threadIdx.y;  // 32 x 8
    #pragma unroll
    for (int dy = 0; dy < 32; dy += 8) {
        size_t idx = (size_t)(r0 + y + dy) * C + c0 + x;
        ushort v;
        if (isb) v = ((const ushort*)src)[idx];
        else { bf16 tb = f2b(((const float*)src)[idx]); v = *(ushort*)&tb; }
        tile[y + dy][x] = v;
    }
    __syncthreads();
    #pragma unroll
    for (int dy = 0; dy < 32; dy += 8)
        dst[(size_t)(c0 + y + dy) * R + r0 + x] = tile[x][y + dy];
}

// ---------------- LayerNorm (raw or f32 input) ----------------
__global__ __launch_bounds__(256) void ln_kernel(
    const void* __restrict__ x, const bf16* __restrict__ w, const bf16* __restrict__ b,
    bf16* __restrict__ out, const int* __restrict__ flag, int force)
{
    bool isb = (force >= 0) ? (force != 0) : (*flag != 0);
    size_t base = (size_t)blockIdx.x * HM;
    int tid = threadIdx.x;
    float v[4], s = 0.f, s2 = 0.f;
    #pragma unroll
    for (int u = 0; u < 4; ++u) {
        size_t idx = base + tid + u * 256;
        float f = isb ? b2f(((const bf16*)x)[idx]) : ((const float*)x)[idx];
        v[u] = f; s += f; s2 += f * f;
    }
    #pragma unroll
    for (int off = 32; off >= 1; off >>= 1) {
        s  += __shfl_down(s, off);
        s2 += __shfl_down(s2, off);
    }
    __shared__ float ra[4], rb[4];
    int wave = tid >> 6;
    if ((tid & 63) == 0) { ra[wave] = s; rb[wave] = s2; }
    __syncthreads();
    s = ra[0] + ra[1] + ra[2] + ra[3];
    s2 = rb[0] + rb[1] + rb[2] + rb[3];
    float mean = s * (1.f / HM);
    float var = fmaxf(s2 * (1.f / HM) - mean * mean, 0.f);
    float rs = rsqrtf(var + 1e-5f);
    #pragma unroll
    for (int u = 0; u < 4; ++u) {
        int col = tid + u * 256;
        out[base + col] = f2b((v[u] - mean) * rs * b2f(w[col]) + b2f(b[col]));
    }
}

// ---------------- gate low-rank MLP ----------------
__global__ __launch_bounds__(256) void gk_kernel(
    const bf16* __restrict__ h, const bf16* __restrict__ w1,
    const bf16* __restrict__ w2, const bf16* __restrict__ b2i,
    bf16* __restrict__ gkout)
{
    size_t row = blockIdx.x;
    const bf16* hr = h + row * HM;
    int tid = threadIdx.x;
    int d = tid & 15, seg = tid >> 4;
    float s = 0.f;
    for (int j = 0; j < 64; ++j) {
        int i = seg * 64 + j;
        s += b2f(hr[i]) * b2f(w1[i * 16 + d]);
    }
    __shared__ float red[256];
    __shared__ float g1[16];
    red[tid] = s;
    __syncthreads();
    if (tid < 16) {
        float t = 0.f;
        #pragma unroll
        for (int sg = 0; sg < 16; ++sg) t += red[sg * 16 + tid];
        g1[tid] = t;
    }
    __syncthreads();
    #pragma unroll
    for (int rep = 0; rep < 2; ++rep) {
        int n = tid + rep * 256;
        float z = b2f(b2i[n]);
        #pragma unroll
        for (int r = 0; r < 16; ++r) z += g1[r] * b2f(w2[r * 512 + n]);
        z = clampf(z, 30.f);
        float ls = (z >= 0.f) ? -log1pf(expf(-z)) : (z - log1pf(expf(z)));
        gkout[row * 512 + n] = f2b(ls * 0.0625f);
    }
}

// ---------------- MFMA GEMM 128x64, BK=64 (round-6, passed) + XCD swizzle ---
// Fragment-order LDS: elem(row,col) -> (row>>4)*1024 + (col>>3)*128
//   + (row&15)*8 + (col&7).   As 128x64 (16KB), Bs 64x64 (8KB).
// 1-D grid gx*gy; if gy%8==0: xcd=flat&7 gets N-band of gy/8 tiles (W band
// <=1MB stays L2-resident per XCD), bm sweeps.
// MODE 0: ->bf16; 1: f32 = resid_raw(flag)+acc; 2: bf16 = gelu(acc+bias);
// MODE 3: resid_f32+acc+bias -> f32 or bf16 per flag
template <int MODE>
__global__ __launch_bounds__(256) void gemm_bt(
    const bf16* __restrict__ A, const bf16* __restrict__ Wt,
    const bf16* __restrict__ bias, const void* __restrict__ resid,
    void* __restrict__ out, int M, int N, int K, const int* __restrict__ oflag)
{
    __shared__ __align__(16) ushort As[128 * 64];
    __shared__ __align__(16) ushort Bs[64 * 64];
    int tid = threadIdx.x;
    int w = tid >> 6, l = tid & 63;

    int gx = M >> 7, gy = N >> 6;
    int flat = blockIdx.x;
    int bm_i, bn_i;
    if ((gy & 7) == 0) {
        int band = gy >> 3;
        int xcd = flat & 7;
        int idx = flat >> 3;
        bn_i = xcd * band + idx % band;
        bm_i = idx / band;
    } else {
        bm_i = flat % gx;
        bn_i = flat / gx;
    }
    int bm = bm_i * 128, bn = bn_i * 64;

    int row16 = l & 15, quad = l >> 4;
    bool isb = false;
    if constexpr (MODE == 1 || MODE == 3) isb = (*oflag != 0);

    const ushort* Au = (const ushort*)A;
    const ushort* Wu = (const ushort*)Wt;

    f32x4 acc[4][2] = {};
    for (int k0 = 0; k0 < K; k0 += 64) {
        #pragma unroll
        for (int i = 0; i < 4; ++i) {
            int j = i * 4 + w;
            const ushort* g = Au + (size_t)(bm + (j >> 1) * 16 + row16) * K
                              + k0 + (j & 1) * 32 + quad * 8;
            GLDS16(g, &As[j * 512 + l * 8]);
        }
        #pragma unroll
        for (int i = 0; i < 2; ++i) {
            int j = i * 4 + w;
            const ushort* g = Wu + (size_t)(bn + (j >> 1) * 16 + row16) * K
                              + k0 + (j & 1) * 32 + quad * 8;
            GLDS16(g, &Bs[j * 512 + l * 8]);
        }
        __syncthreads();
        #pragma unroll
        for (int s = 0; s < 2; ++s) {
            int fo = (s * 4 + quad) * 128 + row16 * 8;
            bf16x8 af[4], bw[2];
            #pragma unroll
            for (int mi = 0; mi < 4; ++mi)
                af[mi] = *(const bf16x8*)&As[((w >> 1) * 4 + mi) * 1024 + fo];
            #pragma unroll
            for (int ni = 0; ni < 2; ++ni)
                bw[ni] = *(const bf16x8*)&Bs[((w & 1) * 2 + ni) * 1024 + fo];
            #pragma unroll
            for (int mi = 0; mi < 4; ++mi)
                #pragma unroll
                for (int ni = 0; ni < 2; ++ni)
                    acc[mi][ni] = __builtin_amdgcn_mfma_f32_16x16x32_bf16(af[mi], bw[ni], acc[mi][ni], 0, 0, 0);
        }
        __syncthreads();
    }
    #pragma unroll
    for (int mi = 0; mi < 4; ++mi) {
        #pragma unroll
        for (int ni = 0; ni < 2; ++ni) {
            int col = bn + (w & 1) * 32 + ni * 16 + row16;
            #pragma unroll
            for (int r = 0; r < 4; ++r) {
                int row = bm + (w >> 1) * 64 + mi * 16 + quad * 4 + r;
                size_t idx = (size_t)row * N + col;
                float v = acc[mi][ni][r];
                if constexpr (MODE == 0) {
                    ((bf16*)out)[idx] = f2b(clampf(v, 1e4f));
                } else if constexpr (MODE == 1) {
                    float rv = isb ? b2f(((const bf16*)resid)[idx])
                                   : ((const float*)resid)[idx];
                    ((float*)out)[idx] = clampf(rv + v, 1e5f);
                } else if constexpr (MODE == 2) {
                    float t = clampf(v + b2f(bias[col]), 50.f);
                    ((bf16*)out)[idx] = f2b(0.5f * t * (1.f + erff(t * 0.70710678f)));
                } else {
                    float t = clampf(v + b2f(bias[col]) + ((const float*)resid)[idx], 2e5f);
                    if (isb) ((bf16*)out)[idx] = f2b(t);
                    else     ((float*)out)[idx] = t;
                }
            }
        }
    }
}

// ---------------- GLA phase 1 (qvg stride 3072) ----------------
__global__ __launch_bounds__(256) void gla_phase1(
    const bf16* __restrict__ gkb,   // [4096][512]
    const bf16* __restrict__ qvg,   // [4096][3072]: q|k|v|g
    float* __restrict__ clbuf, float* __restrict__ Dbuf, float* __restrict__ Pbuf)
{
    int bh = blockIdx.x, c = blockIdx.y;
    int b = bh >> 4, hh = bh & 15;
    int row0 = b * 2048 + c * CHK;
    __shared__ float glog[CHK][DK + 1];
    __shared__ float wk[CHK][DK + 1];
    __shared__ __align__(16) ushort vt[CHK][DV];
    int tid = threadIdx.x;
    int k = tid & 31, i8 = (tid >> 5) * 8;
    #pragma unroll
    for (int u = 0; u < 8; ++u) {
        int i = i8 + u;
        float g = b2f(gkb[(size_t)(row0 + i) * 512 + hh * 32 + k]);
        glog[i][k] = fminf(fmaxf(g, -2.f), 0.f);
    }
    {
        int cc = tid & 7, ii = tid >> 3;
        #pragma unroll
        for (int h = 0; h < 2; ++h) {
            int i = ii + h * 32;
            uint4 val = *(const uint4*)((const ushort*)qvg + (size_t)(row0 + i) * 3072 + 1024 + hh * 64 + cc * 8);
            *(uint4*)&vt[i][cc * 8] = val;
        }
    }
    __syncthreads();
    if (tid < 32) {
        float run = 0.f;
        for (int j = 0; j < CHK; ++j) { run += glog[j][tid]; glog[j][tid] = run; }
    }
    __syncthreads();
    #pragma unroll
    for (int u = 0; u < 8; ++u) {
        int i = i8 + u;
        float cl = glog[i][k];
        float cl63 = glog[CHK - 1][k];
        clbuf[(size_t)(row0 + i) * 512 + hh * 32 + k] = cl;
        wk[i][k] = expf(fmaxf(cl63 - cl, -60.f)) *
            b2f(qvg[(size_t)(row0 + i) * 3072 + 512 + hh * 32 + k]);
    }
    if (tid < 32) Dbuf[(size_t)(bh * 32 + c) * 32 + tid] = expf(glog[CHK - 1][tid]);
    __syncthreads();
    int kk = tid >> 3, v8 = (tid & 7) * 8;
    float acc[8] = {};
    for (int j = 0; j < CHK; ++j) {
        float w = wk[j][kk];
        uint4 raw = *(const uint4*)&vt[j][v8];
        acc8(w, raw, acc);
    }
    float* Pp = Pbuf + (size_t)(bh * 32 + c) * 2048 + kk * 64 + v8;
    #pragma unroll
    for (int u = 0; u < 8; ++u) Pp[u] = acc[u];
}

// ---------------- GLA phase 2: scan ----------------
__global__ __launch_bounds__(256) void gla_scan(
    const float* __restrict__ Pbuf, const float* __restrict__ Dbuf,
    float* __restrict__ Sbuf)
{
    int bh = blockIdx.x >> 3, vg8 = blockIdx.x & 7;
    int kk = threadIdx.x >> 3, vv = vg8 * 8 + (threadIdx.x & 7);
    float S = 0.f;
    for (int c = 0; c < NC; ++c) {
        size_t idx = (size_t)(bh * 32 + c) * 2048 + kk * 64 + vv;
        float P = Pbuf[idx];
        float D = Dbuf[(size_t)(bh * 32 + c) * 32 + kk];
        Sbuf[idx] = S;
        S = D * S + P;
    }
}

// ---------------- GLA phase 3 (qvg stride 3072) ----------------
__global__ __launch_bounds__(256) void gla_phase3(
    const bf16* __restrict__ qvg,
    const float* __restrict__ clbuf, const float* __restrict__ Sbuf,
    const bf16* __restrict__ rmsw, bf16* __restrict__ obuf)
{
    int bh = blockIdx.x, c = blockIdx.y;
    int b = bh >> 4, hh = bh & 15;
    int row0 = b * 2048 + c * CHK;
    __shared__ float qs[CHK][36], ks[CHK][36];
    __shared__ float S0[DK][68];
    __shared__ float Amat[CHK][CHK + 1];
    __shared__ __align__(16) ushort vt[CHK][DV];
    int tid = threadIdx.x;
    {
        int k = tid & 31, i8 = (tid >> 5) * 8;
        #pragma unroll
        for (int u = 0; u < 8; ++u) {
            int i = i8 + u;
            size_t r = (size_t)(row0 + i);
            int col = hh * 32 + k;
            float cl = fmaxf(clbuf[r * 512 + col], -60.f);
            qs[i][k] = b2f(qvg[r * 3072 + col]) * expf(cl) * 0.17677669529663687f;
            ks[i][k] = b2f(qvg[r * 3072 + 512 + col]) * expf(-cl);
        }
    }
    {
        int cc = tid & 7, ii = tid >> 3;
        #pragma unroll
        for (int h = 0; h < 2; ++h) {
            int i = ii + h * 32;
            uint4 val = *(const uint4*)((const ushort*)qvg + (size_t)(row0 + i) * 3072 + 1024 + hh * 64 + cc * 8);
            *(uint4*)&vt[i][cc * 8] = val;
        }
    }
    {
        int kk = tid >> 3, v8 = (tid & 7) * 8;
        const float* Sp = Sbuf + (size_t)(bh * 32 + c) * 2048 + kk * 64 + v8;
        *(f32x4*)&S0[kk][v8]     = *(const f32x4*)Sp;
        *(f32x4*)&S0[kk][v8 + 4] = *(const f32x4*)(Sp + 4);
    }
    __syncthreads();
    int i = tid >> 2, jb = tid & 3;
    for (int jj = 0; jj < 16; ++jj) {
        int j = jb + jj * 4;
        float d = 0.f;
        if (j <= i) {
            const f32x4* qp = (const f32x4*)qs[i];
            const f32x4* kp = (const f32x4*)ks[j];
            #pragma unroll
            for (int q8 = 0; q8 < 8; ++q8) {
                f32x4 a = qp[q8], bq = kp[q8];
                d += a.x * bq.x + a.y * bq.y + a.z * bq.z + a.w * bq.w;
            }
        }
        Amat[i][j] = d;
    }
    __syncthreads();
    float o[16] = {};
    int vv = jb * 16;
    for (int j = 0; j < CHK; ++j) {
        float a = Amat[i][j];
        uint4 r0 = *(const uint4*)&vt[j][vv];
        uint4 r1 = *(const uint4*)&vt[j][vv + 8];
        acc8(a, r0, o);
        acc8(a, r1, o + 8);
    }
    #pragma unroll
    for (int kk = 0; kk < DK; ++kk) {
        float qv = qs[i][kk];
        const f32x4* Sp = (const f32x4*)&S0[kk][vv];
        #pragma unroll
        for (int q4 = 0; q4 < 4; ++q4) {
            f32x4 sv = Sp[q4];
            o[q4 * 4 + 0] += qv * sv.x; o[q4 * 4 + 1] += qv * sv.y;
            o[q4 * 4 + 2] += qv * sv.z; o[q4 * 4 + 3] += qv * sv.w;
        }
    }
    float ss = 0.f;
    #pragma unroll
    for (int u = 0; u < 16; ++u) ss += o[u] * o[u];
    ss += __shfl_xor(ss, 1);
    ss += __shfl_xor(ss, 2);
    float sc = rsqrtf(fmaxf(ss, 0.f) * (1.f / DV) + 1e-5f);
    size_t r = (size_t)(row0 + i);
    #pragma unroll
    for (int u = 0; u < 16; ++u) {
        float g = b2f(qvg[r * 3072 + 2048 + hh * 64 + vv + u]);
        float sw = g / (1.f + expf(-g));
        obuf[r * 1024 + hh * 64 + vv + u] = f2b(clampf(o[u] * sc * b2f(rmsw[vv + u]) * sw, 3e4f));
    }
}

// ---------------- launcher ----------------
extern "C" void kernel_launch(void* const* d_in, const int* in_sizes, int n_in,
                              void* d_out, int out_size, void* d_ws, size_t ws_size,
                              hipStream_t stream) {
    (void)in_sizes; (void)n_in; (void)out_size; (void)ws_size;

    char* ws = (char*)d_ws;
    const size_t MB = 1024 * 1024;
    const size_t KB = 1024;
    bf16*  WqkT = (bf16*)(ws + 0);          // 0-2 MB (combined [3072][1024] with WvgT)
    bf16*  WkT  = (bf16*)(ws + 1 * MB);
    bf16*  WvgT = (bf16*)(ws + 2 * MB);     // 2-6
    bf16*  WgT  = (bf16*)(ws + 4 * MB);
    bf16*  WoT  = (bf16*)(ws + 6 * MB);     // 6-8
    bf16*  W1T  = (bf16*)(ws + 8 * MB);     // 8-12
    bf16*  W2T  = (bf16*)(ws + 12 * MB);    // 12-16
    bf16*  hbuf = (bf16*)(ws + 16 * MB);    // 16-24 (h, later h2)
    bf16*  qvg  = (bf16*)(ws + 24 * MB);    // 24-48 (dead after phase3)
    bf16*  gkb  = (bf16*)(ws + 48 * MB);    // 48-52 (dead after phase1)
    float* clbf = (float*)(ws + 52 * MB);   // 52-60 (dead after phase3)
    float* Dbuf = (float*)(ws + 60 * MB);   // 60-61 (dead after scan)
    float* Pbuf = (float*)(ws + 61 * MB);   // 61-69 (dead after scan)
    float* Sbuf = (float*)(ws + 69 * MB);   // 69-77 (dead after phase3)
    bf16*  obuf = (bf16*)(ws + 61 * MB);    // aliases Pbuf (dead)
    float* ybuf = (float*)(ws + 32 * MB);   // aliases qvg tail (dead after phase3)
    bf16*  f1   = (bf16*)(ws + 48 * MB);    // aliases gkb/clbf/Dbuf/obuf-head (dead)
    bf16*  clnw = (bf16*)(ws + 85 * MB);
    bf16*  clnb = (bf16*)(ws + 85 * MB + 64 * KB);
    bf16*  cgw1 = (bf16*)(ws + 85 * MB + 128 * KB);
    bf16*  cgw2 = (bf16*)(ws + 85 * MB + 192 * KB);
    bf16*  cgb2 = (bf16*)(ws + 85 * MB + 256 * KB);
    bf16*  crms = (bf16*)(ws + 85 * MB + 320 * KB);
    bf16*  cb1  = (bf16*)(ws + 85 * MB + 384 * KB);
    bf16*  cb2  = (bf16*)(ws + 85 * MB + 448 * KB);
    int*   flag = (int*)(ws + 85 * MB + 512 * KB);

    // 1. detect dtype
    hipLaunchKernelGGL(detect_dtype, dim3(1), dim3(256), 0, stream,
                       (const unsigned int*)d_in[0], flag);

    // 2. canonicalize small tensors
    SmallCvt sc;
    sc.s[0] = d_in[1];  sc.d[0] = clnw; sc.n[0] = 1024;
    sc.s[1] = d_in[2];  sc.d[1] = clnb; sc.n[1] = 1024;
    sc.s[2] = d_in[6];  sc.d[2] = cgw1; sc.n[2] = 16384;
    sc.s[3] = d_in[7];  sc.d[3] = cgw2; sc.n[3] = 8192;
    sc.s[4] = d_in[8];  sc.d[4] = cgb2; sc.n[4] = 512;
    sc.s[5] = d_in[10]; sc.d[5] = crms; sc.n[5] = 64;
    sc.s[6] = d_in[13]; sc.d[6] = cb1;  sc.n[6] = 2048;
    sc.s[7] = d_in[15]; sc.d[7] = cb2;  sc.n[7] = 1024;
    hipLaunchKernelGGL(cvt_small, dim3(64), dim3(256), 0, stream, sc, flag);

    // 3. all 7 weight transposes in one launch (8192 tile-blocks)
    TAll ta;
    ta.d[0] = { d_in[3],  (ushort*)WqkT, 1024, 512,  0 };
    ta.d[1] = { d_in[4],  (ushort*)WkT,  1024, 512,  512 };
    ta.d[2] = { d_in[5],  (ushort*)WvgT, 1024, 1024, 1024 };
    ta.d[3] = { d_in[9],  (ushort*)WgT,  1024, 1024, 2048 };
    ta.d[4] = { d_in[11], (ushort*)WoT,  1024, 1024, 3072 };
    ta.d[5] = { d_in[12], (ushort*)W1T,  1024, 2048, 4096 };
    ta.d[6] = { d_in[14], (ushort*)W2T,  2048, 1024, 6144 };
    hipLaunchKernelGGL(transpose_all, dim3(8192), dim3(32, 8), 0, stream, ta, flag);

    // 4. pipeline
    hipLaunchKernelGGL(ln_kernel, dim3(BT), dim3(256), 0, stream,
                       d_in[0], clnw, clnb, hbuf, (const int*)flag, -1);

    hipLaunchKernelGGL((gemm_bt<0>), dim3(32 * 48), dim3(256), 0, stream,
                       hbuf, WqkT, (const bf16*)nullptr, (const void*)nullptr, (void*)qvg, BT, 3072, 1024, flag);
    hipLaunchKernelGGL(gk_kernel, dim3(BT), dim3(256), 0, stream, hbuf, cgw1, cgw2, cgb2, gkb);

    hipLaunchKernelGGL(gla_phase1, dim3(32, 32), dim3(256), 0, stream, gkb, qvg, clbf, Dbuf, Pbuf);
    hipLaunchKernelGGL(gla_scan, dim3(256), dim3(256), 0, stream, Pbuf, Dbuf, Sbuf);
    hipLaunchKernelGGL(gla_phase3, dim3(32, 32), dim3(256), 0, stream, qvg, clbf, Sbuf, crms, obuf);

    hipLaunchKernelGGL((gemm_bt<1>), dim3(32 * 16), dim3(256), 0, stream,
                       obuf, WoT, (const bf16*)nullptr, (const void*)d_in[0], (void*)ybuf, BT, 1024, 1024, flag);
    hipLaunchKernelGGL(ln_kernel, dim3(BT), dim3(256), 0, stream,
                       (const void*)ybuf, clnw, clnb, hbuf, (const int*)flag, 0);
    hipLaunchKernelGGL((gemm_bt<2>), dim3(32 * 32), dim3(256), 0, stream,
                       hbuf, W1T, cb1, (const void*)nullptr, (void*)f1, BT, 2048, 1024, flag);
    hipLaunchKernelGGL((gemm_bt<3>), dim3(32 * 16), dim3(256), 0, stream,
                       f1, W2T, cb2, (const void*)ybuf, d_out, BT, 1024, 2048, flag);
}

// Round 10
// 413.339 us; speedup vs baseline: 1.4707x; 1.0767x over previous
//
#include <hip/hip_runtime.h>
#include <hip/hip_bf16.h>
#include <math.h>

// GLA block, MI355X. Round 10: qvg uses 128x128 GEMM (measured 82.8us r7),
// small GEMMs use 128x64 BK64 (r6) with XCD swizzle reverted (hurt locality,
// FETCH 29->37MB). phase1 serial cumsum -> parallel segmented scan.

using bf16 = __hip_bfloat16;
typedef __attribute__((ext_vector_type(8))) short bf16x8;
typedef __attribute__((ext_vector_type(4))) float f32x4;

#define BT 4096
#define HM 1024
#define DK 32
#define DV 64
#define NC 32
#define CHK 64

#if defined(__has_builtin)
#if __has_builtin(__builtin_amdgcn_global_load_lds)
#define HAVE_GLDS 1
#endif
#endif

#ifdef HAVE_GLDS
#define GLDS16(g, l) __builtin_amdgcn_global_load_lds( \
    (const __attribute__((address_space(1))) unsigned int*)(g), \
    (__attribute__((address_space(3))) unsigned int*)(l), 16, 0, 0)
#else
#define GLDS16(g, l) (*(int4*)(l) = *(const int4*)(g))
#endif

__device__ __forceinline__ float b2f(bf16 v) { return __bfloat162float(v); }
__device__ __forceinline__ bf16 f2b(float v) { return __float2bfloat16(v); }
__device__ __forceinline__ float clampf(float v, float lim) {
    return fminf(fmaxf(v, -lim), lim);
}
__device__ __forceinline__ float lo16(unsigned int u) {
    union { unsigned int i; float f; } c; c.i = u << 16; return c.f;
}
__device__ __forceinline__ float hi16(unsigned int u) {
    union { unsigned int i; float f; } c; c.i = u & 0xffff0000u; return c.f;
}
__device__ __forceinline__ void acc8(float a, uint4 r, float* o) {
    o[0] += a * lo16(r.x); o[1] += a * hi16(r.x);
    o[2] += a * lo16(r.y); o[3] += a * hi16(r.y);
    o[4] += a * lo16(r.z); o[5] += a * hi16(r.z);
    o[6] += a * lo16(r.w); o[7] += a * hi16(r.w);
}

// ---------------- dtype detector ----------------
__global__ __launch_bounds__(256) void detect_dtype(
    const unsigned int* __restrict__ x, int* __restrict__ flag)
{
    int tid = threadIdx.x;
    int cnt = 0;
    for (int i = 0; i < 16; ++i) {
        unsigned int w = x[tid * 16 + i];
        unsigned int e_lo = (w >> 7) & 0xffu;
        unsigned int e_hi = (w >> 23) & 0xffu;
        cnt += (e_lo >= 110 && e_lo <= 135 && e_hi >= 110 && e_hi <= 135) ? 1 : 0;
    }
    __shared__ int red[256];
    red[tid] = cnt;
    __syncthreads();
    for (int s = 128; s > 0; s >>= 1) {
        if (tid < s) red[tid] += red[tid + s];
        __syncthreads();
    }
    if (tid == 0) *flag = (red[0] > 2048) ? 1 : 0;  // 1 = bf16 buffers, 0 = f32
}

// ---------------- fused small-tensor cvt ----------
struct SmallCvt { const void* s[8]; bf16* d[8]; int n[8]; };
__global__ __launch_bounds__(256) void cvt_small(SmallCvt sc, const int* __restrict__ flag)
{
    bool isb = (*flag != 0);
    int stride = gridDim.x * 256;
    #pragma unroll
    for (int seg = 0; seg < 8; ++seg) {
        int n = sc.n[seg];
        for (int i = blockIdx.x * 256 + threadIdx.x; i < n; i += stride) {
            if (isb) ((ushort*)sc.d[seg])[i] = ((const ushort*)sc.s[seg])[i];
            else     sc.d[seg][i] = f2b(((const float*)sc.s[seg])[i]);
        }
    }
}

// ---------------- fused transpose(+cvt) of all 7 weights ---------------------
struct TDesc { const void* src; ushort* dst; int R, C, tile0; };
struct TAll { TDesc d[7]; };
__global__ __launch_bounds__(256) void transpose_all(
    TAll ta, const int* __restrict__ flag)
{
    bool isb = (*flag != 0);
    int bid = blockIdx.x;
    int seg = 0;
    #pragma unroll
    for (int i = 1; i < 7; ++i) if (bid >= ta.d[i].tile0) seg = i;
    const void* src = ta.d[seg].src;
    ushort* dst = ta.d[seg].dst;
    int R = ta.d[seg].R, C = ta.d[seg].C;
    int t = bid - ta.d[seg].tile0;
    int tilesX = C >> 5;
    int c0 = (t % tilesX) * 32, r0 = (t / tilesX) * 32;

    __shared__ ushort tile[32][33];
    int x = threadIdx.x, y = threadIdx.y;  // 32 x 8
    #pragma unroll
    for (int dy = 0; dy < 32; dy += 8) {
        size_t idx = (size_t)(r0 + y + dy) * C + c0 + x;
        ushort v;
        if (isb) v = ((const ushort*)src)[idx];
        else { bf16 tb = f2b(((const float*)src)[idx]); v = *(ushort*)&tb; }
        tile[y + dy][x] = v;
    }
    __syncthreads();
    #pragma unroll
    for (int dy = 0; dy < 32; dy += 8)
        dst[(size_t)(c0 + y + dy) * R + r0 + x] = tile[x][y + dy];
}

// ---------------- LayerNorm (raw or f32 input) ----------------
__global__ __launch_bounds__(256) void ln_kernel(
    const void* __restrict__ x, const bf16* __restrict__ w, const bf16* __restrict__ b,
    bf16* __restrict__ out, const int* __restrict__ flag, int force)
{
    bool isb = (force >= 0) ? (force != 0) : (*flag != 0);
    size_t base = (size_t)blockIdx.x * HM;
    int tid = threadIdx.x;
    float v[4], s = 0.f, s2 = 0.f;
    #pragma unroll
    for (int u = 0; u < 4; ++u) {
        size_t idx = base + tid + u * 256;
        float f = isb ? b2f(((const bf16*)x)[idx]) : ((const float*)x)[idx];
        v[u] = f; s += f; s2 += f * f;
    }
    #pragma unroll
    for (int off = 32; off >= 1; off >>= 1) {
        s  += __shfl_down(s, off);
        s2 += __shfl_down(s2, off);
    }
    __shared__ float ra[4], rb[4];
    int wave = tid >> 6;
    if ((tid & 63) == 0) { ra[wave] = s; rb[wave] = s2; }
    __syncthreads();
    s = ra[0] + ra[1] + ra[2] + ra[3];
    s2 = rb[0] + rb[1] + rb[2] + rb[3];
    float mean = s * (1.f / HM);
    float var = fmaxf(s2 * (1.f / HM) - mean * mean, 0.f);
    float rs = rsqrtf(var + 1e-5f);
    #pragma unroll
    for (int u = 0; u < 4; ++u) {
        int col = tid + u * 256;
        out[base + col] = f2b((v[u] - mean) * rs * b2f(w[col]) + b2f(b[col]));
    }
}

// ---------------- gate low-rank MLP ----------------
__global__ __launch_bounds__(256) void gk_kernel(
    const bf16* __restrict__ h, const bf16* __restrict__ w1,
    const bf16* __restrict__ w2, const bf16* __restrict__ b2i,
    bf16* __restrict__ gkout)
{
    size_t row = blockIdx.x;
    const bf16* hr = h + row * HM;
    int tid = threadIdx.x;
    int d = tid & 15, seg = tid >> 4;
    float s = 0.f;
    for (int j = 0; j < 64; ++j) {
        int i = seg * 64 + j;
        s += b2f(hr[i]) * b2f(w1[i * 16 + d]);
    }
    __shared__ float red[256];
    __shared__ float g1[16];
    red[tid] = s;
    __syncthreads();
    if (tid < 16) {
        float t = 0.f;
        #pragma unroll
        for (int sg = 0; sg < 16; ++sg) t += red[sg * 16 + tid];
        g1[tid] = t;
    }
    __syncthreads();
    #pragma unroll
    for (int rep = 0; rep < 2; ++rep) {
        int n = tid + rep * 256;
        float z = b2f(b2i[n]);
        #pragma unroll
        for (int r = 0; r < 16; ++r) z += g1[r] * b2f(w2[r * 512 + n]);
        z = clampf(z, 30.f);
        float ls = (z >= 0.f) ? -log1pf(expf(-z)) : (z - log1pf(expf(z)));
        gkout[row * 512 + n] = f2b(ls * 0.0625f);
    }
}

// ---------------- MFMA GEMM 128x128, BK=32 (for the big qvg GEMM) -----------
__global__ __launch_bounds__(256) void gemm128(
    const bf16* __restrict__ A, const bf16* __restrict__ Wt,
    void* __restrict__ out, int M, int N, int K)
{
    __shared__ __align__(16) ushort As[128 * 32];
    __shared__ __align__(16) ushort Bs[128 * 32];
    int tid = threadIdx.x;
    int w = tid >> 6, l = tid & 63;
    int bm = blockIdx.x * 128, bn = blockIdx.y * 128;
    int row16 = l & 15, quad = l >> 4;

    const ushort* Au = (const ushort*)A;
    const ushort* Wu = (const ushort*)Wt;

    const ushort* gA0 = Au + (size_t)(bm + w * 16 + row16) * K + quad * 8;
    const ushort* gA1 = Au + (size_t)(bm + (w + 4) * 16 + row16) * K + quad * 8;
    const ushort* gB0 = Wu + (size_t)(bn + w * 16 + row16) * K + quad * 8;
    const ushort* gB1 = Wu + (size_t)(bn + (w + 4) * 16 + row16) * K + quad * 8;
    ushort* lA0 = &As[w * 512 + l * 8];
    ushort* lA1 = &As[(w + 4) * 512 + l * 8];
    ushort* lB0 = &Bs[w * 512 + l * 8];
    ushort* lB1 = &Bs[(w + 4) * 512 + l * 8];

    int fo = quad * 128 + row16 * 8;
    int ab = (w >> 1) * 4;
    int bb = (w & 1) * 4;

    f32x4 acc[4][4] = {};
    for (int k0 = 0; k0 < K; k0 += 32) {
        GLDS16(gA0 + k0, lA0);
        GLDS16(gA1 + k0, lA1);
        GLDS16(gB0 + k0, lB0);
        GLDS16(gB1 + k0, lB1);
        __syncthreads();
        bf16x8 af[4], bw[4];
        #pragma unroll
        for (int mi = 0; mi < 4; ++mi) af[mi] = *(const bf16x8*)&As[(ab + mi) * 512 + fo];
        #pragma unroll
        for (int ni = 0; ni < 4; ++ni) bw[ni] = *(const bf16x8*)&Bs[(bb + ni) * 512 + fo];
        #pragma unroll
        for (int mi = 0; mi < 4; ++mi)
            #pragma unroll
            for (int ni = 0; ni < 4; ++ni)
                acc[mi][ni] = __builtin_amdgcn_mfma_f32_16x16x32_bf16(af[mi], bw[ni], acc[mi][ni], 0, 0, 0);
        __syncthreads();
    }
    #pragma unroll
    for (int mi = 0; mi < 4; ++mi) {
        #pragma unroll
        for (int ni = 0; ni < 4; ++ni) {
            int col = bn + (w & 1) * 64 + ni * 16 + row16;
            #pragma unroll
            for (int r = 0; r < 4; ++r) {
                int row = bm + (w >> 1) * 64 + mi * 16 + quad * 4 + r;
                ((bf16*)out)[(size_t)row * N + col] = f2b(clampf(acc[mi][ni][r], 1e4f));
            }
        }
    }
}

// ---------------- MFMA GEMM 128x64, BK=64 (round-6, no swizzle) -------------
// MODE 1: f32 = resid_raw(flag)+acc; 2: bf16 = gelu(acc+bias);
// MODE 3: resid_f32+acc+bias -> f32 or bf16 per flag
template <int MODE>
__global__ __launch_bounds__(256) void gemm_bt(
    const bf16* __restrict__ A, const bf16* __restrict__ Wt,
    const bf16* __restrict__ bias, const void* __restrict__ resid,
    void* __restrict__ out, int M, int N, int K, const int* __restrict__ oflag)
{
    __shared__ __align__(16) ushort As[128 * 64];
    __shared__ __align__(16) ushort Bs[64 * 64];
    int tid = threadIdx.x;
    int w = tid >> 6, l = tid & 63;
    int bm = blockIdx.x * 128, bn = blockIdx.y * 64;
    int row16 = l & 15, quad = l >> 4;
    bool isb = false;
    if constexpr (MODE == 1 || MODE == 3) isb = (*oflag != 0);

    const ushort* Au = (const ushort*)A;
    const ushort* Wu = (const ushort*)Wt;

    f32x4 acc[4][2] = {};
    for (int k0 = 0; k0 < K; k0 += 64) {
        #pragma unroll
        for (int i = 0; i < 4; ++i) {
            int j = i * 4 + w;
            const ushort* g = Au + (size_t)(bm + (j >> 1) * 16 + row16) * K
                              + k0 + (j & 1) * 32 + quad * 8;
            GLDS16(g, &As[j * 512 + l * 8]);
        }
        #pragma unroll
        for (int i = 0; i < 2; ++i) {
            int j = i * 4 + w;
            const ushort* g = Wu + (size_t)(bn + (j >> 1) * 16 + row16) * K
                              + k0 + (j & 1) * 32 + quad * 8;
            GLDS16(g, &Bs[j * 512 + l * 8]);
        }
        __syncthreads();
        #pragma unroll
        for (int s = 0; s < 2; ++s) {
            int fo = (s * 4 + quad) * 128 + row16 * 8;
            bf16x8 af[4], bw[2];
            #pragma unroll
            for (int mi = 0; mi < 4; ++mi)
                af[mi] = *(const bf16x8*)&As[((w >> 1) * 4 + mi) * 1024 + fo];
            #pragma unroll
            for (int ni = 0; ni < 2; ++ni)
                bw[ni] = *(const bf16x8*)&Bs[((w & 1) * 2 + ni) * 1024 + fo];
            #pragma unroll
            for (int mi = 0; mi < 4; ++mi)
                #pragma unroll
                for (int ni = 0; ni < 2; ++ni)
                    acc[mi][ni] = __builtin_amdgcn_mfma_f32_16x16x32_bf16(af[mi], bw[ni], acc[mi][ni], 0, 0, 0);
        }
        __syncthreads();
    }
    #pragma unroll
    for (int mi = 0; mi < 4; ++mi) {
        #pragma unroll
        for (int ni = 0; ni < 2; ++ni) {
            int col = bn + (w & 1) * 32 + ni * 16 + row16;
            #pragma unroll
            for (int r = 0; r < 4; ++r) {
                int row = bm + (w >> 1) * 64 + mi * 16 + quad * 4 + r;
                size_t idx = (size_t)row * N + col;
                float v = acc[mi][ni][r];
                if constexpr (MODE == 0) {
                    ((bf16*)out)[idx] = f2b(clampf(v, 1e4f));
                } else if constexpr (MODE == 1) {
                    float rv = isb ? b2f(((const bf16*)resid)[idx])
                                   : ((const float*)resid)[idx];
                    ((float*)out)[idx] = clampf(rv + v, 1e5f);
                } else if constexpr (MODE == 2) {
                    float t = clampf(v + b2f(bias[col]), 50.f);
                    ((bf16*)out)[idx] = f2b(0.5f * t * (1.f + erff(t * 0.70710678f)));
                } else {
                    float t = clampf(v + b2f(bias[col]) + ((const float*)resid)[idx], 2e5f);
                    if (isb) ((bf16*)out)[idx] = f2b(t);
                    else     ((float*)out)[idx] = t;
                }
            }
        }
    }
}

// ---------------- GLA phase 1 (parallel segmented scan) ----------------
__global__ __launch_bounds__(256) void gla_phase1(
    const bf16* __restrict__ gkb,   // [4096][512]
    const bf16* __restrict__ qvg,   // [4096][3072]: q|k|v|g
    float* __restrict__ clbuf, float* __restrict__ Dbuf, float* __restrict__ Pbuf)
{
    int bh = blockIdx.x, c = blockIdx.y;
    int b = bh >> 4, hh = bh & 15;
    int row0 = b * 2048 + c * CHK;
    __shared__ float glog[CHK][DK + 1];
    __shared__ float wk[CHK][DK + 1];
    __shared__ float segsum[8][DK + 1];
    __shared__ __align__(16) ushort vt[CHK][DV];
    int tid = threadIdx.x;
    int k = tid & 31, i8 = (tid >> 5) * 8;
    int seg = tid >> 5;
    #pragma unroll
    for (int u = 0; u < 8; ++u) {
        int i = i8 + u;
        float g = b2f(gkb[(size_t)(row0 + i) * 512 + hh * 32 + k]);
        glog[i][k] = fminf(fmaxf(g, -2.f), 0.f);
    }
    {
        int cc = tid & 7, ii = tid >> 3;
        #pragma unroll
        for (int h = 0; h < 2; ++h) {
            int i = ii + h * 32;
            uint4 val = *(const uint4*)((const ushort*)qvg + (size_t)(row0 + i) * 3072 + 1024 + hh * 64 + cc * 8);
            *(uint4*)&vt[i][cc * 8] = val;
        }
    }
    __syncthreads();
    // segmented inclusive scan over i (8 segments of 8 rows per k)
    {
        float run = 0.f;
        #pragma unroll
        for (int u = 0; u < 8; ++u) {
            run += glog[i8 + u][k];
            glog[i8 + u][k] = run;
        }
        segsum[seg][k] = run;
    }
    __syncthreads();
    {
        float off = 0.f;
        for (int s = 0; s < seg; ++s) off += segsum[s][k];
        #pragma unroll
        for (int u = 0; u < 8; ++u) glog[i8 + u][k] += off;
    }
    __syncthreads();
    #pragma unroll
    for (int u = 0; u < 8; ++u) {
        int i = i8 + u;
        float cl = glog[i][k];
        float cl63 = glog[CHK - 1][k];
        clbuf[(size_t)(row0 + i) * 512 + hh * 32 + k] = cl;
        wk[i][k] = expf(fmaxf(cl63 - cl, -60.f)) *
            b2f(qvg[(size_t)(row0 + i) * 3072 + 512 + hh * 32 + k]);
    }
    if (tid < 32) Dbuf[(size_t)(bh * 32 + c) * 32 + tid] = expf(glog[CHK - 1][tid]);
    __syncthreads();
    int kk = tid >> 3, v8 = (tid & 7) * 8;
    float acc[8] = {};
    for (int j = 0; j < CHK; ++j) {
        float w = wk[j][kk];
        uint4 raw = *(const uint4*)&vt[j][v8];
        acc8(w, raw, acc);
    }
    float* Pp = Pbuf + (size_t)(bh * 32 + c) * 2048 + kk * 64 + v8;
    #pragma unroll
    for (int u = 0; u < 8; ++u) Pp[u] = acc[u];
}

// ---------------- GLA phase 2: scan ----------------
__global__ __launch_bounds__(256) void gla_scan(
    const float* __restrict__ Pbuf, const float* __restrict__ Dbuf,
    float* __restrict__ Sbuf)
{
    int bh = blockIdx.x >> 3, vg8 = blockIdx.x & 7;
    int kk = threadIdx.x >> 3, vv = vg8 * 8 + (threadIdx.x & 7);
    float S = 0.f;
    for (int c = 0; c < NC; ++c) {
        size_t idx = (size_t)(bh * 32 + c) * 2048 + kk * 64 + vv;
        float P = Pbuf[idx];
        float D = Dbuf[(size_t)(bh * 32 + c) * 32 + kk];
        Sbuf[idx] = S;
        S = D * S + P;
    }
}

// ---------------- GLA phase 3 (qvg stride 3072) ----------------
__global__ __launch_bounds__(256) void gla_phase3(
    const bf16* __restrict__ qvg,
    const float* __restrict__ clbuf, const float* __restrict__ Sbuf,
    const bf16* __restrict__ rmsw, bf16* __restrict__ obuf)
{
    int bh = blockIdx.x, c = blockIdx.y;
    int b = bh >> 4, hh = bh & 15;
    int row0 = b * 2048 + c * CHK;
    __shared__ float qs[CHK][36], ks[CHK][36];
    __shared__ float S0[DK][68];
    __shared__ float Amat[CHK][CHK + 1];
    __shared__ __align__(16) ushort vt[CHK][DV];
    int tid = threadIdx.x;
    {
        int k = tid & 31, i8 = (tid >> 5) * 8;
        #pragma unroll
        for (int u = 0; u < 8; ++u) {
            int i = i8 + u;
            size_t r = (size_t)(row0 + i);
            int col = hh * 32 + k;
            float cl = fmaxf(clbuf[r * 512 + col], -60.f);
            qs[i][k] = b2f(qvg[r * 3072 + col]) * expf(cl) * 0.17677669529663687f;
            ks[i][k] = b2f(qvg[r * 3072 + 512 + col]) * expf(-cl);
        }
    }
    {
        int cc = tid & 7, ii = tid >> 3;
        #pragma unroll
        for (int h = 0; h < 2; ++h) {
            int i = ii + h * 32;
            uint4 val = *(const uint4*)((const ushort*)qvg + (size_t)(row0 + i) * 3072 + 1024 + hh * 64 + cc * 8);
            *(uint4*)&vt[i][cc * 8] = val;
        }
    }
    {
        int kk = tid >> 3, v8 = (tid & 7) * 8;
        const float* Sp = Sbuf + (size_t)(bh * 32 + c) * 2048 + kk * 64 + v8;
        *(f32x4*)&S0[kk][v8]     = *(const f32x4*)Sp;
        *(f32x4*)&S0[kk][v8 + 4] = *(const f32x4*)(Sp + 4);
    }
    __syncthreads();
    int i = tid >> 2, jb = tid & 3;
    for (int jj = 0; jj < 16; ++jj) {
        int j = jb + jj * 4;
        float d = 0.f;
        if (j <= i) {
            const f32x4* qp = (const f32x4*)qs[i];
            const f32x4* kp = (const f32x4*)ks[j];
            #pragma unroll
            for (int q8 = 0; q8 < 8; ++q8) {
                f32x4 a = qp[q8], bq = kp[q8];
                d += a.x * bq.x + a.y * bq.y + a.z * bq.z + a.w * bq.w;
            }
        }
        Amat[i][j] = d;
    }
    __syncthreads();
    float o[16] = {};
    int vv = jb * 16;
    for (int j = 0; j < CHK; ++j) {
        float a = Amat[i][j];
        uint4 r0 = *(const uint4*)&vt[j][vv];
        uint4 r1 = *(const uint4*)&vt[j][vv + 8];
        acc8(a, r0, o);
        acc8(a, r1, o + 8);
    }
    #pragma unroll
    for (int kk = 0; kk < DK; ++kk) {
        float qv = qs[i][kk];
        const f32x4* Sp = (const f32x4*)&S0[kk][vv];
        #pragma unroll
        for (int q4 = 0; q4 < 4; ++q4) {
            f32x4 sv = Sp[q4];
            o[q4 * 4 + 0] += qv * sv.x; o[q4 * 4 + 1] += qv * sv.y;
            o[q4 * 4 + 2] += qv * sv.z; o[q4 * 4 + 3] += qv * sv.w;
        }
    }
    float ss = 0.f;
    #pragma unroll
    for (int u = 0; u < 16; ++u) ss += o[u] * o[u];
    ss += __shfl_xor(ss, 1);
    ss += __shfl_xor(ss, 2);
    float sc = rsqrtf(fmaxf(ss, 0.f) * (1.f / DV) + 1e-5f);
    size_t r = (size_t)(row0 + i);
    #pragma unroll
    for (int u = 0; u < 16; ++u) {
        float g = b2f(qvg[r * 3072 + 2048 + hh * 64 + vv + u]);
        float sw = g / (1.f + expf(-g));
        obuf[r * 1024 + hh * 64 + vv + u] = f2b(clampf(o[u] * sc * b2f(rmsw[vv + u]) * sw, 3e4f));
    }
}

// ---------------- launcher ----------------
extern "C" void kernel_launch(void* const* d_in, const int* in_sizes, int n_in,
                              void* d_out, int out_size, void* d_ws, size_t ws_size,
                              hipStream_t stream) {
    (void)in_sizes; (void)n_in; (void)out_size; (void)ws_size;

    char* ws = (char*)d_ws;
    const size_t MB = 1024 * 1024;
    const size_t KB = 1024;
    bf16*  WqkT = (bf16*)(ws + 0);          // 0-2 MB (combined [3072][1024] with WvgT)
    bf16*  WkT  = (bf16*)(ws + 1 * MB);
    bf16*  WvgT = (bf16*)(ws + 2 * MB);     // 2-6
    bf16*  WgT  = (bf16*)(ws + 4 * MB);
    bf16*  WoT  = (bf16*)(ws + 6 * MB);     // 6-8
    bf16*  W1T  = (bf16*)(ws + 8 * MB);     // 8-12
    bf16*  W2T  = (bf16*)(ws + 12 * MB);    // 12-16
    bf16*  hbuf = (bf16*)(ws + 16 * MB);    // 16-24 (h, later h2)
    bf16*  qvg  = (bf16*)(ws + 24 * MB);    // 24-48 (dead after phase3)
    bf16*  gkb  = (bf16*)(ws + 48 * MB);    // 48-52 (dead after phase1)
    float* clbf = (float*)(ws + 52 * MB);   // 52-60 (dead after phase3)
    float* Dbuf = (float*)(ws + 60 * MB);   // 60-61 (dead after scan)
    float* Pbuf = (float*)(ws + 61 * MB);   // 61-69 (dead after scan)
    float* Sbuf = (float*)(ws + 69 * MB);   // 69-77 (dead after phase3)
    bf16*  obuf = (bf16*)(ws + 61 * MB);    // aliases Pbuf (dead)
    float* ybuf = (float*)(ws + 32 * MB);   // aliases qvg tail (dead after phase3)
    bf16*  f1   = (bf16*)(ws + 48 * MB);    // aliases gkb/clbf/Dbuf/obuf-head (dead)
    bf16*  clnw = (bf16*)(ws + 85 * MB);
    bf16*  clnb = (bf16*)(ws + 85 * MB + 64 * KB);
    bf16*  cgw1 = (bf16*)(ws + 85 * MB + 128 * KB);
    bf16*  cgw2 = (bf16*)(ws + 85 * MB + 192 * KB);
    bf16*  cgb2 = (bf16*)(ws + 85 * MB + 256 * KB);
    bf16*  crms = (bf16*)(ws + 85 * MB + 320 * KB);
    bf16*  cb1  = (bf16*)(ws + 85 * MB + 384 * KB);
    bf16*  cb2  = (bf16*)(ws + 85 * MB + 448 * KB);
    int*   flag = (int*)(ws + 85 * MB + 512 * KB);

    // 1. detect dtype
    hipLaunchKernelGGL(detect_dtype, dim3(1), dim3(256), 0, stream,
                       (const unsigned int*)d_in[0], flag);

    // 2. canonicalize small tensors
    SmallCvt sc;
    sc.s[0] = d_in[1];  sc.d[0] = clnw; sc.n[0] = 1024;
    sc.s[1] = d_in[2];  sc.d[1] = clnb; sc.n[1] = 1024;
    sc.s[2] = d_in[6];  sc.d[2] = cgw1; sc.n[2] = 16384;
    sc.s[3] = d_in[7];  sc.d[3] = cgw2; sc.n[3] = 8192;
    sc.s[4] = d_in[8];  sc.d[4] = cgb2; sc.n[4] = 512;
    sc.s[5] = d_in[10]; sc.d[5] = crms; sc.n[5] = 64;
    sc.s[6] = d_in[13]; sc.d[6] = cb1;  sc.n[6] = 2048;
    sc.s[7] = d_in[15]; sc.d[7] = cb2;  sc.n[7] = 1024;
    hipLaunchKernelGGL(cvt_small, dim3(64), dim3(256), 0, stream, sc, flag);

    // 3. all 7 weight transposes in one launch
    TAll ta;
    ta.d[0] = { d_in[3],  (ushort*)WqkT, 1024, 512,  0 };
    ta.d[1] = { d_in[4],  (ushort*)WkT,  1024, 512,  512 };
    ta.d[2] = { d_in[5],  (ushort*)WvgT, 1024, 1024, 1024 };
    ta.d[3] = { d_in[9],  (ushort*)WgT,  1024, 1024, 2048 };
    ta.d[4] = { d_in[11], (ushort*)WoT,  1024, 1024, 3072 };
    ta.d[5] = { d_in[12], (ushort*)W1T,  1024, 2048, 4096 };
    ta.d[6] = { d_in[14], (ushort*)W2T,  2048, 1024, 6144 };
    hipLaunchKernelGGL(transpose_all, dim3(8192), dim3(32, 8), 0, stream, ta, flag);

    // 4. pipeline
    hipLaunchKernelGGL(ln_kernel, dim3(BT), dim3(256), 0, stream,
                       d_in[0], clnw, clnb, hbuf, (const int*)flag, -1);

    hipLaunchKernelGGL(gemm128, dim3(32, 24), dim3(256), 0, stream,
                       hbuf, WqkT, (void*)qvg, BT, 3072, 1024);
    hipLaunchKernelGGL(gk_kernel, dim3(BT), dim3(256), 0, stream, hbuf, cgw1, cgw2, cgb2, gkb);

    hipLaunchKernelGGL(gla_phase1, dim3(32, 32), dim3(256), 0, stream, gkb, qvg, clbf, Dbuf, Pbuf);
    hipLaunchKernelGGL(gla_scan, dim3(256), dim3(256), 0, stream, Pbuf, Dbuf, Sbuf);
    hipLaunchKernelGGL(gla_phase3, dim3(32, 32), dim3(256), 0, stream, qvg, clbf, Sbuf, crms, obuf);

    hipLaunchKernelGGL((gemm_bt<1>), dim3(32, 16), dim3(256), 0, stream,
                       obuf, WoT, (const bf16*)nullptr, (const void*)d_in[0], (void*)ybuf, BT, 1024, 1024, flag);
    hipLaunchKernelGGL(ln_kernel, dim3(BT), dim3(256), 0, stream,
                       (const void*)ybuf, clnw, clnb, hbuf, (const int*)flag, 0);
    hipLaunchKernelGGL((gemm_bt<2>), dim3(32, 32), dim3(256), 0, stream,
                       hbuf, W1T, cb1, (const void*)nullptr, (void*)f1, BT, 2048, 1024, flag);
    hipLaunchKernelGGL((gemm_bt<3>), dim3(32, 16), dim3(256), 0, stream,
                       f1, W2T, cb2, (const void*)ybuf, d_out, BT, 1024, 2048, flag);
}

// Round 11
// 404.440 us; speedup vs baseline: 1.5031x; 1.0220x over previous
//
#include <hip/hip_runtime.h>
#include <hip/hip_bf16.h>
#include <math.h>

// GLA block, MI355X. Round 11: gemm128 gets BK=64 (half the barrier drains;
// used for qvg + FFN1 w/ gelu mode); Wo/FFN2 keep 128x64 BK64 (2/CU floor);
// gk fused into first LN (h row via LDS). 12 dispatches.

using bf16 = __hip_bfloat16;
typedef __attribute__((ext_vector_type(8))) short bf16x8;
typedef __attribute__((ext_vector_type(4))) float f32x4;

#define BT 4096
#define HM 1024
#define DK 32
#define DV 64
#define NC 32
#define CHK 64

#if defined(__has_builtin)
#if __has_builtin(__builtin_amdgcn_global_load_lds)
#define HAVE_GLDS 1
#endif
#endif

#ifdef HAVE_GLDS
#define GLDS16(g, l) __builtin_amdgcn_global_load_lds( \
    (const __attribute__((address_space(1))) unsigned int*)(g), \
    (__attribute__((address_space(3))) unsigned int*)(l), 16, 0, 0)
#else
#define GLDS16(g, l) (*(int4*)(l) = *(const int4*)(g))
#endif

__device__ __forceinline__ float b2f(bf16 v) { return __bfloat162float(v); }
__device__ __forceinline__ bf16 f2b(float v) { return __float2bfloat16(v); }
__device__ __forceinline__ float clampf(float v, float lim) {
    return fminf(fmaxf(v, -lim), lim);
}
__device__ __forceinline__ float lo16(unsigned int u) {
    union { unsigned int i; float f; } c; c.i = u << 16; return c.f;
}
__device__ __forceinline__ float hi16(unsigned int u) {
    union { unsigned int i; float f; } c; c.i = u & 0xffff0000u; return c.f;
}
__device__ __forceinline__ void acc8(float a, uint4 r, float* o) {
    o[0] += a * lo16(r.x); o[1] += a * hi16(r.x);
    o[2] += a * lo16(r.y); o[3] += a * hi16(r.y);
    o[4] += a * lo16(r.z); o[5] += a * hi16(r.z);
    o[6] += a * lo16(r.w); o[7] += a * hi16(r.w);
}

// ---------------- dtype detector ----------------
__global__ __launch_bounds__(256) void detect_dtype(
    const unsigned int* __restrict__ x, int* __restrict__ flag)
{
    int tid = threadIdx.x;
    int cnt = 0;
    for (int i = 0; i < 16; ++i) {
        unsigned int w = x[tid * 16 + i];
        unsigned int e_lo = (w >> 7) & 0xffu;
        unsigned int e_hi = (w >> 23) & 0xffu;
        cnt += (e_lo >= 110 && e_lo <= 135 && e_hi >= 110 && e_hi <= 135) ? 1 : 0;
    }
    __shared__ int red[256];
    red[tid] = cnt;
    __syncthreads();
    for (int s = 128; s > 0; s >>= 1) {
        if (tid < s) red[tid] += red[tid + s];
        __syncthreads();
    }
    if (tid == 0) *flag = (red[0] > 2048) ? 1 : 0;  // 1 = bf16 buffers, 0 = f32
}

// ---------------- fused small-tensor cvt ----------
struct SmallCvt { const void* s[8]; bf16* d[8]; int n[8]; };
__global__ __launch_bounds__(256) void cvt_small(SmallCvt sc, const int* __restrict__ flag)
{
    bool isb = (*flag != 0);
    int stride = gridDim.x * 256;
    #pragma unroll
    for (int seg = 0; seg < 8; ++seg) {
        int n = sc.n[seg];
        for (int i = blockIdx.x * 256 + threadIdx.x; i < n; i += stride) {
            if (isb) ((ushort*)sc.d[seg])[i] = ((const ushort*)sc.s[seg])[i];
            else     sc.d[seg][i] = f2b(((const float*)sc.s[seg])[i]);
        }
    }
}

// ---------------- fused transpose(+cvt) of all 7 weights ---------------------
struct TDesc { const void* src; ushort* dst; int R, C, tile0; };
struct TAll { TDesc d[7]; };
__global__ __launch_bounds__(256) void transpose_all(
    TAll ta, const int* __restrict__ flag)
{
    bool isb = (*flag != 0);
    int bid = blockIdx.x;
    int seg = 0;
    #pragma unroll
    for (int i = 1; i < 7; ++i) if (bid >= ta.d[i].tile0) seg = i;
    const void* src = ta.d[seg].src;
    ushort* dst = ta.d[seg].dst;
    int R = ta.d[seg].R, C = ta.d[seg].C;
    int t = bid - ta.d[seg].tile0;
    int tilesX = C >> 5;
    int c0 = (t % tilesX) * 32, r0 = (t / tilesX) * 32;

    __shared__ ushort tile[32][33];
    int x = threadIdx.x, y = threadIdx.y;  // 32 x 8
    #pragma unroll
    for (int dy = 0; dy < 32; dy += 8) {
        size_t idx = (size_t)(r0 + y + dy) * C + c0 + x;
        ushort v;
        if (isb) v = ((const ushort*)src)[idx];
        else { bf16 tb = f2b(((const float*)src)[idx]); v = *(ushort*)&tb; }
        tile[y + dy][x] = v;
    }
    __syncthreads();
    #pragma unroll
    for (int dy = 0; dy < 32; dy += 8)
        dst[(size_t)(c0 + y + dy) * R + r0 + x] = tile[x][y + dy];
}

// ---------------- LayerNorm (+ optional fused gk low-rank MLP) ----------------
template <int DO_GK>
__global__ __launch_bounds__(256) void ln_kernel(
    const void* __restrict__ x, const bf16* __restrict__ w, const bf16* __restrict__ b,
    bf16* __restrict__ out, const int* __restrict__ flag, int force,
    const bf16* __restrict__ w1, const bf16* __restrict__ w2,
    const bf16* __restrict__ b2i, bf16* __restrict__ gkout)
{
    bool isb = (force >= 0) ? (force != 0) : (*flag != 0);
    size_t base = (size_t)blockIdx.x * HM;
    int tid = threadIdx.x;
    float v[4], s = 0.f, s2 = 0.f;
    #pragma unroll
    for (int u = 0; u < 4; ++u) {
        size_t idx = base + tid + u * 256;
        float f = isb ? b2f(((const bf16*)x)[idx]) : ((const float*)x)[idx];
        v[u] = f; s += f; s2 += f * f;
    }
    #pragma unroll
    for (int off = 32; off >= 1; off >>= 1) {
        s  += __shfl_down(s, off);
        s2 += __shfl_down(s2, off);
    }
    __shared__ float ra[4], rb[4];
    __shared__ float hrow[1024];
    int wave = tid >> 6;
    if ((tid & 63) == 0) { ra[wave] = s; rb[wave] = s2; }
    __syncthreads();
    s = ra[0] + ra[1] + ra[2] + ra[3];
    s2 = rb[0] + rb[1] + rb[2] + rb[3];
    float mean = s * (1.f / HM);
    float var = fmaxf(s2 * (1.f / HM) - mean * mean, 0.f);
    float rs = rsqrtf(var + 1e-5f);
    #pragma unroll
    for (int u = 0; u < 4; ++u) {
        int col = tid + u * 256;
        float h = (v[u] - mean) * rs * b2f(w[col]) + b2f(b[col]);
        out[base + col] = f2b(h);
        if constexpr (DO_GK) hrow[col] = h;
    }
    if constexpr (DO_GK) {
        __syncthreads();
        int d = tid & 15, seg = tid >> 4;
        float sg = 0.f;
        #pragma unroll 8
        for (int j = 0; j < 64; ++j) {
            int i = seg * 64 + j;
            sg += hrow[i] * b2f(w1[i * 16 + d]);
        }
        __shared__ float red[256];
        __shared__ float g1[16];
        red[tid] = sg;
        __syncthreads();
        if (tid < 16) {
            float t = 0.f;
            #pragma unroll
            for (int s2i = 0; s2i < 16; ++s2i) t += red[s2i * 16 + tid];
            g1[tid] = t;
        }
        __syncthreads();
        #pragma unroll
        for (int rep = 0; rep < 2; ++rep) {
            int n = tid + rep * 256;
            float z = b2f(b2i[n]);
            #pragma unroll
            for (int r = 0; r < 16; ++r) z += g1[r] * b2f(w2[r * 512 + n]);
            z = clampf(z, 30.f);
            float ls = (z >= 0.f) ? -log1pf(expf(-z)) : (z - log1pf(expf(z)));
            gkout[blockIdx.x * 512 + n] = f2b(ls * 0.0625f);
        }
    }
}

// ---------------- MFMA GEMM 128x128, BK=64 ----------------------------------
// Two 32-wide k-panels per iter; per-panel fragment layout as BK32:
// elem(row,col) -> p*4096 + (row>>4)*512 + ((col&31)>>3)*128 + (row&15)*8 + (col&7)
// Staging (p, j=i*4+w): LDS p*4096 + j*512 + l*8 <-> row j*16+(l&15),
// col p*32+(l>>4)*8. 8 GLDS16/thread, 32 MFMA/wave per iter.
// MODE 0: ->bf16 plain; MODE 2: bf16 = gelu(acc+bias)
template <int MODE>
__global__ __launch_bounds__(256) void gemm128(
    const bf16* __restrict__ A, const bf16* __restrict__ Wt,
    const bf16* __restrict__ bias, void* __restrict__ out, int M, int N, int K)
{
    __shared__ __align__(16) ushort As[128 * 64];
    __shared__ __align__(16) ushort Bs[128 * 64];
    int tid = threadIdx.x;
    int w = tid >> 6, l = tid & 63;
    int bm = blockIdx.x * 128, bn = blockIdx.y * 128;
    int row16 = l & 15, quad = l >> 4;

    const ushort* Au = (const ushort*)A;
    const ushort* Wu = (const ushort*)Wt;

    int ab = (w >> 1) * 4;
    int bb = (w & 1) * 4;

    f32x4 acc[4][4] = {};
    for (int k0 = 0; k0 < K; k0 += 64) {
        #pragma unroll
        for (int p = 0; p < 2; ++p) {
            #pragma unroll
            for (int i = 0; i < 2; ++i) {
                int j = i * 4 + w;
                const ushort* gA = Au + (size_t)(bm + j * 16 + row16) * K
                                   + k0 + p * 32 + quad * 8;
                GLDS16(gA, &As[p * 4096 + j * 512 + l * 8]);
                const ushort* gB = Wu + (size_t)(bn + j * 16 + row16) * K
                                   + k0 + p * 32 + quad * 8;
                GLDS16(gB, &Bs[p * 4096 + j * 512 + l * 8]);
            }
        }
        __syncthreads();
        #pragma unroll
        for (int p = 0; p < 2; ++p) {
            int fo = p * 4096 + quad * 128 + row16 * 8;
            bf16x8 af[4], bw[4];
            #pragma unroll
            for (int mi = 0; mi < 4; ++mi) af[mi] = *(const bf16x8*)&As[(ab + mi) * 512 + fo];
            #pragma unroll
            for (int ni = 0; ni < 4; ++ni) bw[ni] = *(const bf16x8*)&Bs[(bb + ni) * 512 + fo];
            #pragma unroll
            for (int mi = 0; mi < 4; ++mi)
                #pragma unroll
                for (int ni = 0; ni < 4; ++ni)
                    acc[mi][ni] = __builtin_amdgcn_mfma_f32_16x16x32_bf16(af[mi], bw[ni], acc[mi][ni], 0, 0, 0);
        }
        __syncthreads();
    }
    #pragma unroll
    for (int mi = 0; mi < 4; ++mi) {
        #pragma unroll
        for (int ni = 0; ni < 4; ++ni) {
            int col = bn + (w & 1) * 64 + ni * 16 + row16;
            #pragma unroll
            for (int r = 0; r < 4; ++r) {
                int row = bm + (w >> 1) * 64 + mi * 16 + quad * 4 + r;
                size_t idx = (size_t)row * N + col;
                float v = acc[mi][ni][r];
                if constexpr (MODE == 0) {
                    ((bf16*)out)[idx] = f2b(clampf(v, 1e4f));
                } else {
                    float t = clampf(v + b2f(bias[col]), 50.f);
                    ((bf16*)out)[idx] = f2b(0.5f * t * (1.f + erff(t * 0.70710678f)));
                }
            }
        }
    }
}

// ---------------- MFMA GEMM 128x64, BK=64 (Wo / FFN2) -----------------------
// MODE 1: f32 = resid_raw(flag)+acc; MODE 3: resid_f32+acc+bias -> per flag
template <int MODE>
__global__ __launch_bounds__(256) void gemm_bt(
    const bf16* __restrict__ A, const bf16* __restrict__ Wt,
    const bf16* __restrict__ bias, const void* __restrict__ resid,
    void* __restrict__ out, int M, int N, int K, const int* __restrict__ oflag)
{
    __shared__ __align__(16) ushort As[128 * 64];
    __shared__ __align__(16) ushort Bs[64 * 64];
    int tid = threadIdx.x;
    int w = tid >> 6, l = tid & 63;
    int bm = blockIdx.x * 128, bn = blockIdx.y * 64;
    int row16 = l & 15, quad = l >> 4;
    bool isb = (*oflag != 0);

    const ushort* Au = (const ushort*)A;
    const ushort* Wu = (const ushort*)Wt;

    f32x4 acc[4][2] = {};
    for (int k0 = 0; k0 < K; k0 += 64) {
        #pragma unroll
        for (int i = 0; i < 4; ++i) {
            int j = i * 4 + w;
            const ushort* g = Au + (size_t)(bm + (j >> 1) * 16 + row16) * K
                              + k0 + (j & 1) * 32 + quad * 8;
            GLDS16(g, &As[j * 512 + l * 8]);
        }
        #pragma unroll
        for (int i = 0; i < 2; ++i) {
            int j = i * 4 + w;
            const ushort* g = Wu + (size_t)(bn + (j >> 1) * 16 + row16) * K
                              + k0 + (j & 1) * 32 + quad * 8;
            GLDS16(g, &Bs[j * 512 + l * 8]);
        }
        __syncthreads();
        #pragma unroll
        for (int s = 0; s < 2; ++s) {
            int fo = (s * 4 + quad) * 128 + row16 * 8;
            bf16x8 af[4], bw[2];
            #pragma unroll
            for (int mi = 0; mi < 4; ++mi)
                af[mi] = *(const bf16x8*)&As[((w >> 1) * 4 + mi) * 1024 + fo];
            #pragma unroll
            for (int ni = 0; ni < 2; ++ni)
                bw[ni] = *(const bf16x8*)&Bs[((w & 1) * 2 + ni) * 1024 + fo];
            #pragma unroll
            for (int mi = 0; mi < 4; ++mi)
                #pragma unroll
                for (int ni = 0; ni < 2; ++ni)
                    acc[mi][ni] = __builtin_amdgcn_mfma_f32_16x16x32_bf16(af[mi], bw[ni], acc[mi][ni], 0, 0, 0);
        }
        __syncthreads();
    }
    #pragma unroll
    for (int mi = 0; mi < 4; ++mi) {
        #pragma unroll
        for (int ni = 0; ni < 2; ++ni) {
            int col = bn + (w & 1) * 32 + ni * 16 + row16;
            #pragma unroll
            for (int r = 0; r < 4; ++r) {
                int row = bm + (w >> 1) * 64 + mi * 16 + quad * 4 + r;
                size_t idx = (size_t)row * N + col;
                float v = acc[mi][ni][r];
                if constexpr (MODE == 1) {
                    float rv = isb ? b2f(((const bf16*)resid)[idx])
                                   : ((const float*)resid)[idx];
                    ((float*)out)[idx] = clampf(rv + v, 1e5f);
                } else {
                    float t = clampf(v + b2f(bias[col]) + ((const float*)resid)[idx], 2e5f);
                    if (isb) ((bf16*)out)[idx] = f2b(t);
                    else     ((float*)out)[idx] = t;
                }
            }
        }
    }
}

// ---------------- GLA phase 1 (parallel segmented scan) ----------------
__global__ __launch_bounds__(256) void gla_phase1(
    const bf16* __restrict__ gkb, const bf16* __restrict__ qvg,
    float* __restrict__ clbuf, float* __restrict__ Dbuf, float* __restrict__ Pbuf)
{
    int bh = blockIdx.x, c = blockIdx.y;
    int b = bh >> 4, hh = bh & 15;
    int row0 = b * 2048 + c * CHK;
    __shared__ float glog[CHK][DK + 1];
    __shared__ float wk[CHK][DK + 1];
    __shared__ float segsum[8][DK + 1];
    __shared__ __align__(16) ushort vt[CHK][DV];
    int tid = threadIdx.x;
    int k = tid & 31, i8 = (tid >> 5) * 8;
    int seg = tid >> 5;
    #pragma unroll
    for (int u = 0; u < 8; ++u) {
        int i = i8 + u;
        float g = b2f(gkb[(size_t)(row0 + i) * 512 + hh * 32 + k]);
        glog[i][k] = fminf(fmaxf(g, -2.f), 0.f);
    }
    {
        int cc = tid & 7, ii = tid >> 3;
        #pragma unroll
        for (int h = 0; h < 2; ++h) {
            int i = ii + h * 32;
            uint4 val = *(const uint4*)((const ushort*)qvg + (size_t)(row0 + i) * 3072 + 1024 + hh * 64 + cc * 8);
            *(uint4*)&vt[i][cc * 8] = val;
        }
    }
    __syncthreads();
    {
        float run = 0.f;
        #pragma unroll
        for (int u = 0; u < 8; ++u) {
            run += glog[i8 + u][k];
            glog[i8 + u][k] = run;
        }
        segsum[seg][k] = run;
    }
    __syncthreads();
    {
        float off = 0.f;
        for (int s = 0; s < seg; ++s) off += segsum[s][k];
        #pragma unroll
        for (int u = 0; u < 8; ++u) glog[i8 + u][k] += off;
    }
    __syncthreads();
    #pragma unroll
    for (int u = 0; u < 8; ++u) {
        int i = i8 + u;
        float cl = glog[i][k];
        float cl63 = glog[CHK - 1][k];
        clbuf[(size_t)(row0 + i) * 512 + hh * 32 + k] = cl;
        wk[i][k] = expf(fmaxf(cl63 - cl, -60.f)) *
            b2f(qvg[(size_t)(row0 + i) * 3072 + 512 + hh * 32 + k]);
    }
    if (tid < 32) Dbuf[(size_t)(bh * 32 + c) * 32 + tid] = expf(glog[CHK - 1][tid]);
    __syncthreads();
    int kk = tid >> 3, v8 = (tid & 7) * 8;
    float acc[8] = {};
    for (int j = 0; j < CHK; ++j) {
        float w = wk[j][kk];
        uint4 raw = *(const uint4*)&vt[j][v8];
        acc8(w, raw, acc);
    }
    float* Pp = Pbuf + (size_t)(bh * 32 + c) * 2048 + kk * 64 + v8;
    #pragma unroll
    for (int u = 0; u < 8; ++u) Pp[u] = acc[u];
}

// ---------------- GLA phase 2: scan ----------------
__global__ __launch_bounds__(256) void gla_scan(
    const float* __restrict__ Pbuf, const float* __restrict__ Dbuf,
    float* __restrict__ Sbuf)
{
    int bh = blockIdx.x >> 3, vg8 = blockIdx.x & 7;
    int kk = threadIdx.x >> 3, vv = vg8 * 8 + (threadIdx.x & 7);
    float S = 0.f;
    for (int c = 0; c < NC; ++c) {
        size_t idx = (size_t)(bh * 32 + c) * 2048 + kk * 64 + vv;
        float P = Pbuf[idx];
        float D = Dbuf[(size_t)(bh * 32 + c) * 32 + kk];
        Sbuf[idx] = S;
        S = D * S + P;
    }
}

// ---------------- GLA phase 3 ----------------
__global__ __launch_bounds__(256) void gla_phase3(
    const bf16* __restrict__ qvg,
    const float* __restrict__ clbuf, const float* __restrict__ Sbuf,
    const bf16* __restrict__ rmsw, bf16* __restrict__ obuf)
{
    int bh = blockIdx.x, c = blockIdx.y;
    int b = bh >> 4, hh = bh & 15;
    int row0 = b * 2048 + c * CHK;
    __shared__ float qs[CHK][36], ks[CHK][36];
    __shared__ float S0[DK][68];
    __shared__ float Amat[CHK][CHK + 1];
    __shared__ __align__(16) ushort vt[CHK][DV];
    int tid = threadIdx.x;
    {
        int k = tid & 31, i8 = (tid >> 5) * 8;
        #pragma unroll
        for (int u = 0; u < 8; ++u) {
            int i = i8 + u;
            size_t r = (size_t)(row0 + i);
            int col = hh * 32 + k;
            float cl = fmaxf(clbuf[r * 512 + col], -60.f);
            qs[i][k] = b2f(qvg[r * 3072 + col]) * expf(cl) * 0.17677669529663687f;
            ks[i][k] = b2f(qvg[r * 3072 + 512 + col]) * expf(-cl);
        }
    }
    {
        int cc = tid & 7, ii = tid >> 3;
        #pragma unroll
        for (int h = 0; h < 2; ++h) {
            int i = ii + h * 32;
            uint4 val = *(const uint4*)((const ushort*)qvg + (size_t)(row0 + i) * 3072 + 1024 + hh * 64 + cc * 8);
            *(uint4*)&vt[i][cc * 8] = val;
        }
    }
    {
        int kk = tid >> 3, v8 = (tid & 7) * 8;
        const float* Sp = Sbuf + (size_t)(bh * 32 + c) * 2048 + kk * 64 + v8;
        *(f32x4*)&S0[kk][v8]     = *(const f32x4*)Sp;
        *(f32x4*)&S0[kk][v8 + 4] = *(const f32x4*)(Sp + 4);
    }
    __syncthreads();
    int i = tid >> 2, jb = tid & 3;
    for (int jj = 0; jj < 16; ++jj) {
        int j = jb + jj * 4;
        float d = 0.f;
        if (j <= i) {
            const f32x4* qp = (const f32x4*)qs[i];
            const f32x4* kp = (const f32x4*)ks[j];
            #pragma unroll
            for (int q8 = 0; q8 < 8; ++q8) {
                f32x4 a = qp[q8], bq = kp[q8];
                d += a.x * bq.x + a.y * bq.y + a.z * bq.z + a.w * bq.w;
            }
        }
        Amat[i][j] = d;
    }
    __syncthreads();
    float o[16] = {};
    int vv = jb * 16;
    for (int j = 0; j < CHK; ++j) {
        float a = Amat[i][j];
        uint4 r0 = *(const uint4*)&vt[j][vv];
        uint4 r1 = *(const uint4*)&vt[j][vv + 8];
        acc8(a, r0, o);
        acc8(a, r1, o + 8);
    }
    #pragma unroll
    for (int kk = 0; kk < DK; ++kk) {
        float qv = qs[i][kk];
        const f32x4* Sp = (const f32x4*)&S0[kk][vv];
        #pragma unroll
        for (int q4 = 0; q4 < 4; ++q4) {
            f32x4 sv = Sp[q4];
            o[q4 * 4 + 0] += qv * sv.x; o[q4 * 4 + 1] += qv * sv.y;
            o[q4 * 4 + 2] += qv * sv.z; o[q4 * 4 + 3] += qv * sv.w;
        }
    }
    float ss = 0.f;
    #pragma unroll
    for (int u = 0; u < 16; ++u) ss += o[u] * o[u];
    ss += __shfl_xor(ss, 1);
    ss += __shfl_xor(ss, 2);
    float sc = rsqrtf(fmaxf(ss, 0.f) * (1.f / DV) + 1e-5f);
    size_t r = (size_t)(row0 + i);
    #pragma unroll
    for (int u = 0; u < 16; ++u) {
        float g = b2f(qvg[r * 3072 + 2048 + hh * 64 + vv + u]);
        float sw = g / (1.f + expf(-g));
        obuf[r * 1024 + hh * 64 + vv + u] = f2b(clampf(o[u] * sc * b2f(rmsw[vv + u]) * sw, 3e4f));
    }
}

// ---------------- launcher ----------------
extern "C" void kernel_launch(void* const* d_in, const int* in_sizes, int n_in,
                              void* d_out, int out_size, void* d_ws, size_t ws_size,
                              hipStream_t stream) {
    (void)in_sizes; (void)n_in; (void)out_size; (void)ws_size;

    char* ws = (char*)d_ws;
    const size_t MB = 1024 * 1024;
    const size_t KB = 1024;
    bf16*  WqkT = (bf16*)(ws + 0);
    bf16*  WkT  = (bf16*)(ws + 1 * MB);
    bf16*  WvgT = (bf16*)(ws + 2 * MB);
    bf16*  WgT  = (bf16*)(ws + 4 * MB);
    bf16*  WoT  = (bf16*)(ws + 6 * MB);
    bf16*  W1T  = (bf16*)(ws + 8 * MB);
    bf16*  W2T  = (bf16*)(ws + 12 * MB);
    bf16*  hbuf = (bf16*)(ws + 16 * MB);
    bf16*  qvg  = (bf16*)(ws + 24 * MB);
    bf16*  gkb  = (bf16*)(ws + 48 * MB);
    float* clbf = (float*)(ws + 52 * MB);
    float* Dbuf = (float*)(ws + 60 * MB);
    float* Pbuf = (float*)(ws + 61 * MB);
    float* Sbuf = (float*)(ws + 69 * MB);
    bf16*  obuf = (bf16*)(ws + 61 * MB);
    float* ybuf = (float*)(ws + 32 * MB);
    bf16*  f1   = (bf16*)(ws + 48 * MB);
    bf16*  clnw = (bf16*)(ws + 85 * MB);
    bf16*  clnb = (bf16*)(ws + 85 * MB + 64 * KB);
    bf16*  cgw1 = (bf16*)(ws + 85 * MB + 128 * KB);
    bf16*  cgw2 = (bf16*)(ws + 85 * MB + 192 * KB);
    bf16*  cgb2 = (bf16*)(ws + 85 * MB + 256 * KB);
    bf16*  crms = (bf16*)(ws + 85 * MB + 320 * KB);
    bf16*  cb1  = (bf16*)(ws + 85 * MB + 384 * KB);
    bf16*  cb2  = (bf16*)(ws + 85 * MB + 448 * KB);
    int*   flag = (int*)(ws + 85 * MB + 512 * KB);

    hipLaunchKernelGGL(detect_dtype, dim3(1), dim3(256), 0, stream,
                       (const unsigned int*)d_in[0], flag);

    SmallCvt sc;
    sc.s[0] = d_in[1];  sc.d[0] = clnw; sc.n[0] = 1024;
    sc.s[1] = d_in[2];  sc.d[1] = clnb; sc.n[1] = 1024;
    sc.s[2] = d_in[6];  sc.d[2] = cgw1; sc.n[2] = 16384;
    sc.s[3] = d_in[7];  sc.d[3] = cgw2; sc.n[3] = 8192;
    sc.s[4] = d_in[8];  sc.d[4] = cgb2; sc.n[4] = 512;
    sc.s[5] = d_in[10]; sc.d[5] = crms; sc.n[5] = 64;
    sc.s[6] = d_in[13]; sc.d[6] = cb1;  sc.n[6] = 2048;
    sc.s[7] = d_in[15]; sc.d[7] = cb2;  sc.n[7] = 1024;
    hipLaunchKernelGGL(cvt_small, dim3(64), dim3(256), 0, stream, sc, flag);

    TAll ta;
    ta.d[0] = { d_in[3],  (ushort*)WqkT, 1024, 512,  0 };
    ta.d[1] = { d_in[4],  (ushort*)WkT,  1024, 512,  512 };
    ta.d[2] = { d_in[5],  (ushort*)WvgT, 1024, 1024, 1024 };
    ta.d[3] = { d_in[9],  (ushort*)WgT,  1024, 1024, 2048 };
    ta.d[4] = { d_in[11], (ushort*)WoT,  1024, 1024, 3072 };
    ta.d[5] = { d_in[12], (ushort*)W1T,  1024, 2048, 4096 };
    ta.d[6] = { d_in[14], (ushort*)W2T,  2048, 1024, 6144 };
    hipLaunchKernelGGL(transpose_all, dim3(8192), dim3(32, 8), 0, stream, ta, flag);

    // LN1 + fused gk
    hipLaunchKernelGGL((ln_kernel<1>), dim3(BT), dim3(256), 0, stream,
                       d_in[0], clnw, clnb, hbuf, (const int*)flag, -1,
                       cgw1, cgw2, cgb2, gkb);

    hipLaunchKernelGGL((gemm128<0>), dim3(32, 24), dim3(256), 0, stream,
                       hbuf, WqkT, (const bf16*)nullptr, (void*)qvg, BT, 3072, 1024);

    hipLaunchKernelGGL(gla_phase1, dim3(32, 32), dim3(256), 0, stream, gkb, qvg, clbf, Dbuf, Pbuf);
    hipLaunchKernelGGL(gla_scan, dim3(256), dim3(256), 0, stream, Pbuf, Dbuf, Sbuf);
    hipLaunchKernelGGL(gla_phase3, dim3(32, 32), dim3(256), 0, stream, qvg, clbf, Sbuf, crms, obuf);

    hipLaunchKernelGGL((gemm_bt<1>), dim3(32, 16), dim3(256), 0, stream,
                       obuf, WoT, (const bf16*)nullptr, (const void*)d_in[0], (void*)ybuf, BT, 1024, 1024, flag);
    hipLaunchKernelGGL((ln_kernel<0>), dim3(BT), dim3(256), 0, stream,
                       (const void*)ybuf, clnw, clnb, hbuf, (const int*)flag, 0,
                       (const bf16*)nullptr, (const bf16*)nullptr, (const bf16*)nullptr, (bf16*)nullptr);
    hipLaunchKernelGGL((gemm128<2>), dim3(32, 16), dim3(256), 0, stream,
                       hbuf, W1T, cb1, (void*)f1, BT, 2048, 1024);
    hipLaunchKernelGGL((gemm_bt<3>), dim3(32, 16), dim3(256), 0, stream,
                       f1, W2T, cb2, (const void*)ybuf, d_out, BT, 1024, 2048, flag);
}